// Round 15
// baseline (813.718 us; speedup 1.0000x reference)
//
#include <hip/hip_runtime.h>
#include <stdint.h>

typedef unsigned short u16;
typedef unsigned short bf16u;
typedef unsigned int u32;
typedef _Float16 f16;
typedef __attribute__((ext_vector_type(8))) short bf16x8;
typedef __attribute__((ext_vector_type(8))) _Float16 f16x8;
typedef __attribute__((ext_vector_type(4))) float f32x4;

#define T_N 2048
#define H_N 2048
#define S_N 1024
#define B_N 2
#define HQ_N 16
#define HKV_N 4
#define D_N 128
#define E_N 32
#define K_TOP 4
#define CAP_N 512
#define IM_N 512
#define SIM_N 1024
#define QD_N 2048
#define KD_N 512
#define QKV_N 3072
#define NFLAT (T_N*K_TOP)
#define RGRP 128
#define NGRP (NFLAT/RGRP)

#define SC_H1   1024.0f
#define SC_W    512.0f
#define SC_QK   2048.0f
#define SC_P    4096.0f
#define SC_V    2048.0f
#define OSC_QKV (1.0f/524288.0f)
#define OSC_OPJ (1.0f/1048576.0f)

__device__ __forceinline__ float bf2f(bf16u x){ return __uint_as_float(((u32)x)<<16); }
__device__ __forceinline__ bf16u f2bf(float f){
  u32 u = __float_as_uint(f);
  u32 r = (u + 0x7FFFu + ((u>>16)&1u)) >> 16;
  return (bf16u)r;
}
__device__ __forceinline__ u32 pkbf(float a, float b){
  u32 ua = __float_as_uint(a), ub = __float_as_uint(b);
  u32 ra = (ua + 0x7FFFu + ((ua>>16)&1u)) >> 16;
  u32 rb = (ub + 0x7FFFu + ((ub>>16)&1u)) & 0xFFFF0000u;
  return ra | rb;
}
__device__ __forceinline__ void split2h(float x, u16& h, u16& l){
  f16 hh = (f16)x;
  f16 ll = (f16)(x - (float)hh);
  h = __builtin_bit_cast(u16, hh);
  l = __builtin_bit_cast(u16, ll);
}
__device__ __forceinline__ f32x4 mfma16b(bf16x8 a, bf16x8 b, f32x4 c){
  return __builtin_amdgcn_mfma_f32_16x16x32_bf16(a,b,c,0,0,0);
}
__device__ __forceinline__ f32x4 mfma16h(f16x8 a, f16x8 b, f32x4 c){
  return __builtin_amdgcn_mfma_f32_16x16x32_f16(a,b,c,0,0,0);
}
__device__ __forceinline__ void gl_lds16(const void* g, void* l){
  __builtin_amdgcn_global_load_lds((const __attribute__((address_space(1))) u32*)g,
                                   (__attribute__((address_space(3))) u32*)l, 16, 0, 0);
}
template<int N> __device__ __forceinline__ void waitv(){
  if constexpr (N==0) asm volatile("s_waitcnt vmcnt(0)" ::: "memory");
  else if constexpr (N==2) asm volatile("s_waitcnt vmcnt(2)" ::: "memory");
  else if constexpr (N==3) asm volatile("s_waitcnt vmcnt(3)" ::: "memory");
  else if constexpr (N==4) asm volatile("s_waitcnt vmcnt(4)" ::: "memory");
  else if constexpr (N==8) asm volatile("s_waitcnt vmcnt(8)" ::: "memory");
  __builtin_amdgcn_sched_barrier(0);
}
__device__ __forceinline__ int xcd_swz(int lin, int nwg){
  int cpx = nwg >> 3;
  return (lin & 7)*cpx + (lin >> 3);
}

// ---------------- fp32 transpose (gate_w only, C=32)
__global__ __launch_bounds__(256) void transpose_f32(const float* __restrict__ in,
                                                     float* __restrict__ out, int R, int C){
  __shared__ float tile[32][33];
  int rb = blockIdx.x*32, cb = blockIdx.y*32;
  int tx = threadIdx.x, ty = threadIdx.y;
  #pragma unroll
  for (int kk=0;kk<4;kk++)
    tile[ty+kk*8][tx] = in[(size_t)(rb+ty+kk*8)*C + cb + tx];
  __syncthreads();
  #pragma unroll
  for (int kk=0;kk<4;kk++)
    out[(size_t)(cb+ty+kk*8)*R + rb + tx] = tile[tx][ty+kk*8];
}

// ---------------- fast transpose + fp32->bf16
__global__ __launch_bounds__(256) void transpose_cvt_g(const float* __restrict__ in,
                                                       bf16u* __restrict__ out, int R, int C){
  __shared__ float tile[64*64];
  size_t zo = (size_t)blockIdx.z * R * C;
  int rb = blockIdx.x*64, cb = blockIdx.y*64;
  int tid = threadIdx.x, wave = tid>>6, lane = tid&63;
  #pragma unroll
  for (int p=0;p<4;p++){
    int r = p*16 + wave*4 + (lane>>4);
    const float* src = in + zo + (size_t)(rb + r)*C + cb + (lane&15)*4;
    gl_lds16(src, &tile[(p*16 + wave*4)*64]);
  }
  __syncthreads();
  int c = tid>>2, rq = (tid&3)*16;
  u16 tmp[16];
  #pragma unroll
  for (int j=0;j<16;j++) tmp[j] = f2bf(tile[(rq+j)*64 + c]);
  uint4 w0, w1;
  w0.x=(u32)tmp[0]|((u32)tmp[1]<<16);  w0.y=(u32)tmp[2]|((u32)tmp[3]<<16);
  w0.z=(u32)tmp[4]|((u32)tmp[5]<<16);  w0.w=(u32)tmp[6]|((u32)tmp[7]<<16);
  w1.x=(u32)tmp[8]|((u32)tmp[9]<<16);  w1.y=(u32)tmp[10]|((u32)tmp[11]<<16);
  w1.z=(u32)tmp[12]|((u32)tmp[13]<<16); w1.w=(u32)tmp[14]|((u32)tmp[15]<<16);
  bf16u* dst = out + zo + (size_t)(cb+c)*R + rb + rq;
  *(uint4*)dst = w0;
  *(uint4*)(dst+8) = w1;
}

// ---------------- fast transpose + f16 split (scaled)
__global__ __launch_bounds__(256) void transpose_split16_g(const float* __restrict__ in,
                                                           u16* __restrict__ oh,
                                                           u16* __restrict__ ol,
                                                           int R, int C, float scale){
  __shared__ float tile[64*64];
  int rb = blockIdx.x*64, cb = blockIdx.y*64;
  int tid = threadIdx.x, wave = tid>>6, lane = tid&63;
  #pragma unroll
  for (int p=0;p<4;p++){
    int r = p*16 + wave*4 + (lane>>4);
    const float* src = in + (size_t)(rb + r)*C + cb + (lane&15)*4;
    gl_lds16(src, &tile[(p*16 + wave*4)*64]);
  }
  __syncthreads();
  int c = tid>>2, rq = (tid&3)*16;
  u16 th[16], tl[16];
  #pragma unroll
  for (int j=0;j<16;j++) split2h(tile[(rq+j)*64 + c]*scale, th[j], tl[j]);
  uint4 h0, h1, l0, l1;
  h0.x=(u32)th[0]|((u32)th[1]<<16);  h0.y=(u32)th[2]|((u32)th[3]<<16);
  h0.z=(u32)th[4]|((u32)th[5]<<16);  h0.w=(u32)th[6]|((u32)th[7]<<16);
  h1.x=(u32)th[8]|((u32)th[9]<<16);  h1.y=(u32)th[10]|((u32)th[11]<<16);
  h1.z=(u32)th[12]|((u32)th[13]<<16); h1.w=(u32)th[14]|((u32)th[15]<<16);
  l0.x=(u32)tl[0]|((u32)tl[1]<<16);  l0.y=(u32)tl[2]|((u32)tl[3]<<16);
  l0.z=(u32)tl[4]|((u32)tl[5]<<16);  l0.w=(u32)tl[6]|((u32)tl[7]<<16);
  l1.x=(u32)tl[8]|((u32)tl[9]<<16);  l1.y=(u32)tl[10]|((u32)tl[11]<<16);
  l1.z=(u32)tl[12]|((u32)tl[13]<<16); l1.w=(u32)tl[14]|((u32)tl[15]<<16);
  size_t o = (size_t)(cb+c)*R + rb + rq;
  *(uint4*)(oh + o) = h0; *(uint4*)(oh + o + 8) = h1;
  *(uint4*)(ol + o) = l0; *(uint4*)(ol + o + 8) = l1;
}

// ---------------- RMSNorm fp32 -> bf16
__global__ __launch_bounds__(256) void rmsnorm_bf16(const float* __restrict__ x,
                                                    const float* __restrict__ w,
                                                    bf16u* __restrict__ y){
  int row = blockIdx.x; int t = threadIdx.x;
  const float4* x4 = (const float4*)(x + (size_t)row*H_N);
  float4 a = x4[2*t], b = x4[2*t+1];
  float ss = a.x*a.x+a.y*a.y+a.z*a.z+a.w*a.w + b.x*b.x+b.y*b.y+b.z*b.z+b.w*b.w;
  #pragma unroll
  for (int m=32;m>=1;m>>=1) ss += __shfl_xor(ss,m,64);
  __shared__ float red[4];
  if ((t&63)==0) red[t>>6]=ss;
  __syncthreads();
  float scale = rsqrtf((red[0]+red[1]+red[2]+red[3])*(1.0f/H_N) + 1e-6f);
  const float4* w4 = (const float4*)w;
  float4 wa = w4[2*t], wb = w4[2*t+1];
  uint4 pk;
  pk.x = pkbf(a.x*scale*wa.x, a.y*scale*wa.y);
  pk.y = pkbf(a.z*scale*wa.z, a.w*scale*wa.w);
  pk.z = pkbf(b.x*scale*wb.x, b.y*scale*wb.y);
  pk.w = pkbf(b.z*scale*wb.z, b.w*scale*wb.w);
  ((uint4*)(y + (size_t)row*H_N))[t] = pk;
}

// ---------------- RMSNorm fp32 -> f16 split (scaled)
__global__ __launch_bounds__(256) void rmsnorm_f16split(const float* __restrict__ x,
                                                        const float* __restrict__ w,
                                                        u16* __restrict__ yh,
                                                        u16* __restrict__ yl){
  int row = blockIdx.x; int t = threadIdx.x;
  const float4* x4 = (const float4*)(x + (size_t)row*H_N);
  float4 a = x4[2*t], b = x4[2*t+1];
  float ss = a.x*a.x+a.y*a.y+a.z*a.z+a.w*a.w + b.x*b.x+b.y*b.y+b.z*b.z+b.w*b.w;
  #pragma unroll
  for (int m=32;m>=1;m>>=1) ss += __shfl_xor(ss,m,64);
  __shared__ float red[4];
  if ((t&63)==0) red[t>>6]=ss;
  __syncthreads();
  float scale = rsqrtf((red[0]+red[1]+red[2]+red[3])*(1.0f/H_N) + 1e-6f) * SC_H1;
  const float4* w4 = (const float4*)w;
  float4 wa = w4[2*t], wb = w4[2*t+1];
  float o[8] = {a.x*scale*wa.x, a.y*scale*wa.y, a.z*scale*wa.z, a.w*scale*wa.w,
                b.x*scale*wb.x, b.y*scale*wb.y, b.z*scale*wb.z, b.w*scale*wb.w};
  u16 hh[8], ll[8];
  #pragma unroll
  for (int j=0;j<8;j++) split2h(o[j], hh[j], ll[j]);
  uint4 pk, pl;
  pk.x = (u32)hh[0]|((u32)hh[1]<<16); pk.y = (u32)hh[2]|((u32)hh[3]<<16);
  pk.z = (u32)hh[4]|((u32)hh[5]<<16); pk.w = (u32)hh[6]|((u32)hh[7]<<16);
  pl.x = (u32)ll[0]|((u32)ll[1]<<16); pl.y = (u32)ll[2]|((u32)ll[3]<<16);
  pl.z = (u32)ll[4]|((u32)ll[5]<<16); pl.w = (u32)ll[6]|((u32)ll[7]<<16);
  ((uint4*)(yh + (size_t)row*H_N))[t] = pk;
  ((uint4*)(yl + (size_t)row*H_N))[t] = pl;
}

// ---------------- qk-norm + neox RoPE (fp64 trig)
__global__ void qknorm_rope_split(const float* __restrict__ qkv,
                                  const float* __restrict__ qw, const float* __restrict__ kw,
                                  const int* __restrict__ positions,
                                  u16* __restrict__ qho, u16* __restrict__ qlo,
                                  u16* __restrict__ kho, u16* __restrict__ klo){
  int t = blockIdx.x; int hy = blockIdx.y; int l = threadIdx.x;
  const float* p; const float* w; u16 *oh, *ol; size_t obase;
  if (hy < HQ_N){
    p = qkv + (size_t)t*QKV_N + hy*D_N; w = qw;
    oh = qho; ol = qlo; obase = (size_t)t*QD_N + hy*D_N;
  } else {
    p = qkv + (size_t)t*QKV_N + QD_N + (hy-HQ_N)*D_N; w = kw;
    oh = kho; ol = klo; obase = (size_t)t*KD_N + (hy-HQ_N)*D_N;
  }
  float x0 = p[l], x1 = p[l+64];
  float ss = x0*x0 + x1*x1;
  #pragma unroll
  for (int m=32;m>=1;m>>=1) ss += __shfl_xor(ss,m,64);
  float scale = rsqrtf(ss*(1.0f/D_N)+1e-6f);
  x0 *= scale*w[l]; x1 *= scale*w[l+64];
  double freq = exp2(-(double)l * (19.931568569324174/64.0));
  double fr = (double)positions[t] * freq;
  double sd, cd; sincos(fr, &sd, &cd);
  float r0 = (float)((double)x0*cd - (double)x1*sd) * SC_QK;
  float r1 = (float)((double)x1*cd + (double)x0*sd) * SC_QK;
  u16 hh, ll;
  split2h(r0, hh, ll); oh[obase+l] = hh; ol[obase+l] = ll;
  split2h(r1, hh, ll); oh[obase+l+64] = hh; ol[obase+l+64] = ll;
}

// ---------------- V transpose + f16 split (scaled)
__global__ __launch_bounds__(256) void transpose_v_split(const float* __restrict__ in,
                                                         u16* __restrict__ oh,
                                                         u16* __restrict__ ol){
  __shared__ u16 th[32][33];
  __shared__ u16 tl[32][33];
  int z = blockIdx.z; int b = z >> 2, kvh = z & 3;
  const float* ip = in + (size_t)b*S_N*QKV_N + QD_N + KD_N + kvh*D_N;
  size_t ob = (size_t)z*D_N*S_N;
  int sb = blockIdx.x*32, db = blockIdx.y*32;
  int tx=threadIdx.x, ty=threadIdx.y;
  #pragma unroll
  for (int kk=0;kk<4;kk++){
    float x = ip[(size_t)(sb+ty+kk*8)*QKV_N + db+tx] * SC_V;
    u16 hh, ll; split2h(x, hh, ll);
    th[ty+kk*8][tx] = hh; tl[ty+kk*8][tx] = ll;
  }
  __syncthreads();
  #pragma unroll
  for (int kk=0;kk<4;kk++){
    size_t idx = ob + (size_t)(db+ty+kk*8)*S_N + sb+tx;
    oh[idx] = th[tx][ty+kk*8];
    ol[idx] = tl[tx][ty+kk*8];
  }
}

// ---------------- SPLIT GEMM: 4 waves, 64x64 per-wave tile, swizzled LDS,
// counted-vmcnt pipeline. C = (Ah+Al)(Bh+Bl)^T 3-pass, f32 out*oscale (+resid).
__global__ __launch_bounds__(256) void gemm_split64(
    const u16* __restrict__ Ah, const u16* __restrict__ Al,
    const u16* __restrict__ Bh, const u16* __restrict__ Bl,
    float* __restrict__ Cout, const float* __restrict__ resid, float oscale,
    int N, int Kd)
{
  __shared__ u16 AsH[2][128*32];
  __shared__ u16 AsL[2][128*32];
  __shared__ u16 BsH[2][128*32];
  __shared__ u16 BsL[2][128*32];

  int tid = threadIdx.x;
  int wave = tid>>6, lane = tid&63, l15 = lane&15, lg = lane>>4;
  int sw = (l15>>1)&3;
  int nwgx = gridDim.x;
  int lin = blockIdx.y*nwgx + blockIdx.x;
  int swz = xcd_swz(lin, nwgx*gridDim.y);
  int mBase = (swz % nwgx)*128;
  int nBase = (swz / nwgx)*128;
  int wm = wave>>1, wn = wave&1;

  size_t aOff[2], bOff[2];
  #pragma unroll
  for (int i=0;i<2;i++){
    int le = i*256 + tid;
    int r = le >> 2;
    int cc = (((le&3) ^ ((r>>1)&3)))*8;
    aOff[i] = (size_t)(mBase + r)*Kd + cc;
    bOff[i] = (size_t)(nBase + r)*Kd + cc;
  }

  auto STAGE = [&](int buf, int kt){
    size_t ko = (size_t)kt*32;
    #pragma unroll
    for (int i=0;i<2;i++){
      int lo = (i*256 + tid)*8;
      gl_lds16(Ah + aOff[i] + ko, &AsH[buf][lo]);
      gl_lds16(Al + aOff[i] + ko, &AsL[buf][lo]);
      gl_lds16(Bh + bOff[i] + ko, &BsH[buf][lo]);
      gl_lds16(Bl + bOff[i] + ko, &BsL[buf][lo]);
    }
  };

  f32x4 zero4 = {0.f,0.f,0.f,0.f};
  f32x4 acc[4][4];
  #pragma unroll
  for (int mi=0;mi<4;mi++)
    #pragma unroll
    for (int ni=0;ni<4;ni++) acc[mi][ni] = zero4;

  int kread = (lg ^ sw)*8;
  int nK = Kd >> 5;
  STAGE(0, 0);
  for (int kt=0; kt<nK; kt++){
    int cur = kt&1;
    if (kt+1 < nK){ STAGE(cur^1, kt+1); waitv<8>(); }
    else waitv<0>();
    __builtin_amdgcn_s_barrier();
    __builtin_amdgcn_sched_barrier(0);
    f16x8 ah[4], al[4];
    #pragma unroll
    for (int mi=0;mi<4;mi++){
      ah[mi] = *(const f16x8*)&AsH[cur][(wm*64 + mi*16 + l15)*32 + kread];
      al[mi] = *(const f16x8*)&AsL[cur][(wm*64 + mi*16 + l15)*32 + kread];
    }
    __builtin_amdgcn_s_setprio(1);
    #pragma unroll
    for (int ni=0;ni<4;ni++){
      f16x8 bh = *(const f16x8*)&BsH[cur][(wn*64 + ni*16 + l15)*32 + kread];
      f16x8 bl = *(const f16x8*)&BsL[cur][(wn*64 + ni*16 + l15)*32 + kread];
      #pragma unroll
      for (int mi=0;mi<4;mi++){
        acc[mi][ni] = mfma16h(ah[mi], bh, acc[mi][ni]);
        acc[mi][ni] = mfma16h(ah[mi], bl, acc[mi][ni]);
        acc[mi][ni] = mfma16h(al[mi], bh, acc[mi][ni]);
      }
    }
    __builtin_amdgcn_s_setprio(0);
    asm volatile("s_waitcnt lgkmcnt(0)" ::: "memory");
    __builtin_amdgcn_sched_barrier(0);
    __builtin_amdgcn_s_barrier();
  }

  #pragma unroll
  for (int mi=0;mi<4;mi++){
    #pragma unroll
    for (int ni=0;ni<4;ni++){
      #pragma unroll
      for (int i=0;i<4;i++){
        int rloc = wm*64 + mi*16 + 4*lg + i;
        int col  = nBase + wn*64 + ni*16 + l15;
        size_t idx = (size_t)(mBase + rloc)*N + col;
        Cout[idx] = acc[mi][ni][i]*oscale + (resid ? resid[idx] : 0.0f);
      }
    }
  }
}

// ---------------- dense GEMM, 8-wave 512thr, XCD+LDS swizzle, counted-vmcnt
// MODE 1: f32 out*oscale (+resid). MODE 2: silu(g)*u bf16 (dual B).
template<int MODE>
__global__ __launch_bounds__(512) void gemm_bt8(
    const u16* __restrict__ A,
    const u16* __restrict__ B0g, const u16* __restrict__ B1g,
    void* __restrict__ Cout, const float* __restrict__ resid, float oscale,
    int N, int Kd)
{
  constexpr bool DUAL = (MODE==2);
  constexpr int LD = DUAL ? 3 : 2;
  __shared__ u16 As[2][128*32];
  __shared__ u16 Bs0[2][128*32];
  __shared__ u16 Bs1[DUAL?2:1][DUAL?128*32:8];

  int tid = threadIdx.x;
  int wave = tid>>6, lane = tid&63, l15 = lane&15, lg = lane>>4;
  int sw = (l15>>1)&3;
  int nwgx = gridDim.x;
  int lin = blockIdx.y*nwgx + blockIdx.x;
  int swz = xcd_swz(lin, nwgx*gridDim.y);
  int mBase = (swz % nwgx)*128;
  int nBase = (swz / nwgx)*128;

  int r = tid>>2;
  int c = (((tid&3) ^ ((r>>1)&3)))*8;
  size_t aOff = (size_t)(mBase + r)*Kd + c;
  size_t bOff = (size_t)(nBase + r)*Kd + c;

  auto STAGE = [&](int buf, int kt){
    size_t ko = (size_t)kt*32;
    gl_lds16(A + aOff + ko, &As[buf][tid*8]);
    gl_lds16(B0g + bOff + ko, &Bs0[buf][tid*8]);
    if constexpr (DUAL){
      gl_lds16(B1g + bOff + ko, &Bs1[buf][tid*8]);
    }
  };

  f32x4 zero4 = {0.f,0.f,0.f,0.f};
  f32x4 acc0[2][4];
  f32x4 acc1[DUAL?2:1][DUAL?4:1];
  #pragma unroll
  for (int mi=0;mi<2;mi++)
    #pragma unroll
    for (int ni=0;ni<4;ni++){
      acc0[mi][ni] = zero4;
      if constexpr (DUAL) acc1[mi][ni] = zero4;
    }

  int wm = wave>>1, wn = wave&1;
  int kread = ((lg ^ sw))*8;
  int nK = Kd >> 5;
  STAGE(0, 0);
  for (int kt=0; kt<nK; kt++){
    int cur = kt&1;
    if (kt+1 < nK){ STAGE(cur^1, kt+1); waitv<LD>(); }
    else waitv<0>();
    __builtin_amdgcn_s_barrier();
    __builtin_amdgcn_sched_barrier(0);
    bf16x8 af[2];
    #pragma unroll
    for (int mi=0;mi<2;mi++)
      af[mi] = *(const bf16x8*)&As[cur][(wm*32 + mi*16 + l15)*32 + kread];
    __builtin_amdgcn_s_setprio(1);
    #pragma unroll
    for (int ni=0;ni<4;ni++){
      bf16x8 b0 = *(const bf16x8*)&Bs0[cur][(wn*64 + ni*16 + l15)*32 + kread];
      #pragma unroll
      for (int mi=0;mi<2;mi++) acc0[mi][ni] = mfma16b(af[mi], b0, acc0[mi][ni]);
      if constexpr (DUAL){
        bf16x8 b1 = *(const bf16x8*)&Bs1[cur][(wn*64 + ni*16 + l15)*32 + kread];
        #pragma unroll
        for (int mi=0;mi<2;mi++) acc1[mi][ni] = mfma16b(af[mi], b1, acc1[mi][ni]);
      }
    }
    __builtin_amdgcn_s_setprio(0);
    asm volatile("s_waitcnt lgkmcnt(0)" ::: "memory");
    __builtin_amdgcn_sched_barrier(0);
    __builtin_amdgcn_s_barrier();
  }

  #pragma unroll
  for (int mi=0;mi<2;mi++){
    #pragma unroll
    for (int ni=0;ni<4;ni++){
      #pragma unroll
      for (int i=0;i<4;i++){
        int rloc = wm*32 + mi*16 + 4*lg + i;
        int col  = nBase + wn*64 + ni*16 + l15;
        float v = acc0[mi][ni][i];
        if constexpr (MODE==1){
          size_t idx = (size_t)(mBase + rloc)*N + col;
          ((float*)Cout)[idx] = v*oscale + (resid ? resid[idx] : 0.0f);
        } else {
          float u = acc1[mi][ni][i];
          float sv = v/(1.0f+__expf(-v))*u;
          ((bf16u*)Cout)[(size_t)(mBase + rloc)*N + col] = f2bf(sv);
        }
      }
    }
  }
}

// ---------------- MoE gate/up: counted-vmcnt, 8 waves, XCD+LDS swizzle
__global__ __launch_bounds__(512) void moe_gu8w(
    const u16* __restrict__ A,
    const u16* __restrict__ B0g,
    const u16* __restrict__ B1g,
    bf16u* __restrict__ Out,
    const int* __restrict__ starts, const int* __restrict__ counts,
    const int* __restrict__ perm)
{
  __shared__ u16 As[2][128*32];
  __shared__ u16 Bs0[2][128*32];
  __shared__ u16 Bs1[2][128*32];

  int nwgx = gridDim.x, nwgy = gridDim.y;
  int lin = (blockIdx.z*nwgy + blockIdx.y)*nwgx + blockIdx.x;
  int swzi = xcd_swz(lin, nwgx*nwgy*gridDim.z);
  int bx = swzi % nwgx; swzi /= nwgx;
  int by = swzi % nwgy;
  int e  = swzi / nwgy;

  int cnt = counts[e]; cnt = cnt < CAP_N ? cnt : CAP_N;
  int mBase = bx*128;
  int rows = cnt - mBase;
  if (rows <= 0) return;
  if (rows > 128) rows = 128;
  int slotBase = starts[e] + mBase;
  int nBase = by*128;
  const u16* Bp0 = B0g + (size_t)e*IM_N*H_N;
  const u16* Bp1 = B1g + (size_t)e*IM_N*H_N;

  int tid = threadIdx.x, wave = tid>>6, lane = tid&63, l15 = lane&15, lg = lane>>4;
  int sw = (l15>>1)&3;
  int r = tid>>2;
  int c = (((tid&3) ^ ((r>>1)&3)))*8;
  int rr = (r < rows) ? r : 0;
  size_t aOff = (size_t)perm[slotBase + rr]*H_N + c;
  size_t bOff = (size_t)(nBase + r)*H_N + c;

  auto STAGE = [&](int buf, int kt){
    size_t ko = (size_t)kt*32;
    gl_lds16(A + aOff + ko, &As[buf][tid*8]);
    gl_lds16(Bp0 + bOff + ko, &Bs0[buf][tid*8]);
    gl_lds16(Bp1 + bOff + ko, &Bs1[buf][tid*8]);
  };

  f32x4 zero4 = {0.f,0.f,0.f,0.f};
  f32x4 acc0[2][4], acc1[2][4];
  #pragma unroll
  for (int mi=0;mi<2;mi++)
    #pragma unroll
    for (int ni=0;ni<4;ni++){ acc0[mi][ni]=zero4; acc1[mi][ni]=zero4; }

  int wm = wave>>1, wn = wave&1;
  int kread = ((lg ^ sw))*8;
  STAGE(0, 0);
  int nK = H_N >> 5;
  for (int kt=0; kt<nK; kt++){
    int cur = kt&1;
    if (kt+1 < nK){ STAGE(cur^1, kt+1); waitv<3>(); }
    else waitv<0>();
    __builtin_amdgcn_s_barrier();
    __builtin_amdgcn_sched_barrier(0);
    bf16x8 af[2];
    #pragma unroll
    for (int mi=0;mi<2;mi++)
      af[mi] = *(const bf16x8*)&As[cur][(wm*32 + mi*16 + l15)*32 + kread];
    __builtin_amdgcn_s_setprio(1);
    #pragma unroll
    for (int ni=0;ni<4;ni++){
      bf16x8 b0 = *(const bf16x8*)&Bs0[cur][(wn*64 + ni*16 + l15)*32 + kread];
      bf16x8 b1 = *(const bf16x8*)&Bs1[cur][(wn*64 + ni*16 + l15)*32 + kread];
      #pragma unroll
      for (int mi=0;mi<2;mi++){
        acc0[mi][ni] = mfma16b(af[mi], b0, acc0[mi][ni]);
        acc1[mi][ni] = mfma16b(af[mi], b1, acc1[mi][ni]);
      }
    }
    __builtin_amdgcn_s_setprio(0);
    asm volatile("s_waitcnt lgkmcnt(0)" ::: "memory");
    __builtin_amdgcn_sched_barrier(0);
    __builtin_amdgcn_s_barrier();
  }

  #pragma unroll
  for (int mi=0;mi<2;mi++){
    #pragma unroll
    for (int ni=0;ni<4;ni++){
      #pragma unroll
      for (int i=0;i<4;i++){
        int rloc = wm*32 + mi*16 + 4*lg + i;
        if (rloc < rows){
          float v = acc0[mi][ni][i];
          float u = acc1[mi][ni][i];
          float sv = v/(1.0f+__expf(-v))*u;
          Out[(size_t)(slotBase + rloc)*IM_N + nBase + wn*64 + ni*16 + l15] = f2bf(sv);
        }
      }
    }
  }
}

// ---------------- MoE down: counted-vmcnt, 8 waves, XCD+LDS swizzle
__global__ __launch_bounds__(512) void moe_down8w(
    const u16* __restrict__ A,
    const u16* __restrict__ B0g,
    bf16u* __restrict__ Out,
    const int* __restrict__ starts, const int* __restrict__ counts)
{
  __shared__ u16 As[2][128*32];
  __shared__ u16 Bs0[2][128*32];

  int nwgx = gridDim.x, nwgy = gridDim.y;
  int lin = (blockIdx.z*nwgy + blockIdx.y)*nwgx + blockIdx.x;
  int swzi = xcd_swz(lin, nwgx*nwgy*gridDim.z);
  int bx = swzi % nwgx; swzi /= nwgx;
  int by = swzi % nwgy;
  int e  = swzi / nwgy;

  int cnt = counts[e]; cnt = cnt < CAP_N ? cnt : CAP_N;
  int mBase = bx*128;
  int rows = cnt - mBase;
  if (rows <= 0) return;
  if (rows > 128) rows = 128;
  int slotBase = starts[e] + mBase;
  int nBase = by*128;
  const u16* Bp0 = B0g + (size_t)e*H_N*IM_N;

  int tid = threadIdx.x, wave = tid>>6, lane = tid&63, l15 = lane&15, lg = lane>>4;
  int sw = (l15>>1)&3;
  int r = tid>>2;
  int c = (((tid&3) ^ ((r>>1)&3)))*8;
  int rr = (r < rows) ? r : 0;
  size_t aOff = (size_t)(slotBase + rr)*IM_N + c;
  size_t bOff = (size_t)(nBase + r)*IM_N + c;

  auto STAGE = [&](int buf, int kt){
    size_t ko = (size_t)kt*32;
    gl_lds16(A + aOff + ko, &As[buf][tid*8]);
    gl_lds16(Bp0 + bOff + ko, &Bs0[buf][tid*8]);
  };

  f32x4 zero4 = {0.f,0.f,0.f,0.f};
  f32x4 acc0[2][4];
  #pragma unroll
  for (int mi=0;mi<2;mi++)
    #pragma unroll
    for (int ni=0;ni<4;ni++) acc0[mi][ni]=zero4;

  int wm = wave>>1, wn = wave&1;
  int kread = ((lg ^ sw))*8;
  STAGE(0, 0);
  int nK = IM_N >> 5;
  for (int kt=0; kt<nK; kt++){
    int cur = kt&1;
    if (kt+1 < nK){ STAGE(cur^1, kt+1); waitv<2>(); }
    else waitv<0>();
    __builtin_amdgcn_s_barrier();
    __builtin_amdgcn_sched_barrier(0);
    bf16x8 af[2];
    #pragma unroll
    for (int mi=0;mi<2;mi++)
      af[mi] = *(const bf16x8*)&As[cur][(wm*32 + mi*16 + l15)*32 + kread];
    __builtin_amdgcn_s_setprio(1);
    #pragma unroll
    for (int ni=0;ni<4;ni++){
      bf16x8 b0 = *(const bf16x8*)&Bs0[cur][(wn*64 + ni*16 + l15)*32 + kread];
      #pragma unroll
      for (int mi=0;mi<2;mi++)
        acc0[mi][ni] = mfma16b(af[mi], b0, acc0[mi][ni]);
    }
    __builtin_amdgcn_s_setprio(0);
    asm volatile("s_waitcnt lgkmcnt(0)" ::: "memory");
    __builtin_amdgcn_sched_barrier(0);
    __builtin_amdgcn_s_barrier();
  }

  #pragma unroll
  for (int mi=0;mi<2;mi++){
    #pragma unroll
    for (int ni=0;ni<4;ni++){
      #pragma unroll
      for (int i=0;i<4;i++){
        int rloc = wm*32 + mi*16 + 4*lg + i;
        if (rloc < rows)
          Out[(size_t)(slotBase + rloc)*H_N + nBase + wn*64 + ni*16 + l15] = f2bf(acc0[mi][ni][i]);
      }
    }
  }
}

// ---------------- flash attention, causal GQA, f16 split, 8-wave paired q-tiles
__global__ __launch_bounds__(512) void attn_kernel(
    const u16* __restrict__ qh, const u16* __restrict__ ql,
    const u16* __restrict__ kh, const u16* __restrict__ kl,
    const u16* __restrict__ vth, const u16* __restrict__ vtl,
    u16* __restrict__ aoh, u16* __restrict__ aol)
{
  int bx = blockIdx.x;
  int bh = blockIdx.y;
  int b = bh >> 4, h = bh & 15, kvh = h >> 2;
  int tid = threadIdx.x, wave = tid>>6, lane = tid&63, l15 = lane&15, lg = lane>>4;

  __shared__ u16 Ksh[64*136];
  __shared__ u16 Ksl[64*136];
  __shared__ u16 Vsh[128*72];
  __shared__ u16 Vsl[128*72];
  __shared__ u16 Psh[8][16*72];
  __shared__ u16 Psl[8][16*72];

  int qtile = (wave < 4) ? bx : (15 - bx);
  int wl = wave & 3;
  int qrow0 = qtile*64 + wl*16;

  size_t qrow = (size_t)(b*S_N + qrow0 + l15)*QD_N + h*D_N;
  f16x8 qfh[4], qfl[4];
  #pragma unroll
  for (int ds=0; ds<4; ds++){
    qfh[ds] = *(const f16x8*)(qh + qrow + ds*32 + lg*8);
    qfl[ds] = *(const f16x8*)(ql + qrow + ds*32 + lg*8);
  }

  f32x4 zero4 = {0.f,0.f,0.f,0.f};
  f32x4 accO[8];
  #pragma unroll
  for (int dc=0; dc<8; dc++) accO[dc] = zero4;
  float mrun[4], lrun[4];
  #pragma unroll
  for (int i=0;i<4;i++){ mrun[i] = -3.0e38f; lrun[i] = 0.0f; }

  const float SC_S = 0.08838834764831845f * (1.0f/(SC_QK*SC_QK));
  int nkt = 16 - bx;
  for (int kt=0; kt<nkt; kt++){
    #pragma unroll
    for (int pp=0; pp<2; pp++){
      int r = pp*32 + (tid>>4), c = (tid&15)*8;
      size_t go = (size_t)(b*S_N + kt*64 + r)*KD_N + kvh*D_N + c;
      *(f16x8*)&Ksh[r*136 + c] = *(const f16x8*)(kh + go);
      *(f16x8*)&Ksl[r*136 + c] = *(const f16x8*)(kl + go);
    }
    #pragma unroll
    for (int pp=0; pp<2; pp++){
      int r = pp*64 + (tid>>3), c = (tid&7)*8;
      size_t go = ((size_t)(b*HKV_N + kvh)*D_N + r)*S_N + kt*64 + c;
      *(f16x8*)&Vsh[r*72 + c] = *(const f16x8*)(vth + go);
      *(f16x8*)&Vsl[r*72 + c] = *(const f16x8*)(vtl + go);
    }
    __syncthreads();

    bool active = (kt <= qtile);
    if (active){
      f32x4 sacc[4];
      #pragma unroll
      for (int kc=0;kc<4;kc++){
        sacc[kc] = zero4;
        #pragma unroll
        for (int ds=0; ds<4; ds++){
          f16x8 kfh = *(const f16x8*)&Ksh[(kc*16 + l15)*136 + ds*32 + lg*8];
          f16x8 kfl = *(const f16x8*)&Ksl[(kc*16 + l15)*136 + ds*32 + lg*8];
          sacc[kc] = mfma16h(qfh[ds], kfh, sacc[kc]);
          sacc[kc] = mfma16h(qfh[ds], kfl, sacc[kc]);
          sacc[kc] = mfma16h(qfl[ds], kfh, sacc[kc]);
        }
      }

      float pv[4][4];
      bool maskT = (kt == qtile);
      #pragma unroll
      for (int kc=0;kc<4;kc++)
        #pragma unroll
        for (int i=0;i<4;i++){
          float sv = sacc[kc][i] * SC_S;
          if (maskT){
            int kg = kt*64 + kc*16 + l15;
            int qg = qrow0 + 4*lg + i;
            if (kg > qg) sv = -3.0e38f;
          }
          pv[kc][i] = sv;
        }

      #pragma unroll
      for (int i=0;i<4;i++){
        float mx = fmaxf(fmaxf(pv[0][i],pv[1][i]),fmaxf(pv[2][i],pv[3][i]));
        #pragma unroll
        for (int mm=1; mm<16; mm<<=1) mx = fmaxf(mx, __shfl_xor(mx, mm, 64));
        float mnew = fmaxf(mrun[i], mx);
        float corr = exp2f((mrun[i]-mnew)*1.44269504f);
        float ps = 0.f;
        #pragma unroll
        for (int kc=0;kc<4;kc++){
          float p = exp2f((pv[kc][i]-mnew)*1.44269504f);
          pv[kc][i] = p; ps += p;
        }
        #pragma unroll
        for (int mm=1; mm<16; mm<<=1) ps += __shfl_xor(ps, mm, 64);
        lrun[i] = lrun[i]*corr + ps;
        mrun[i] = mnew;
        #pragma unroll
        for (int dc=0;dc<8;dc++) accO[dc][i] *= corr;
      }

      #pragma unroll
      for (int kc=0;kc<4;kc++)
        #pragma unroll
        for (int i=0;i<4;i++){
          u16 hh, ll; split2h(pv[kc][i]*SC_P, hh, ll);
          Psh[wave][(4*lg+i)*72 + kc*16 + l15] = hh;
          Psl[wave][(4*lg+i)*72 + kc*16 + l15] = ll;
        }
      asm volatile("s_waitcnt lgkmcnt(0)" ::: "memory");
      __builtin_amdgcn_sched_barrier(0);

      #pragma unroll
      for (int ks=0; ks<2; ks++){
        f16x8 pfh = *(const f16x8*)&Psh[wave][l15*72 + ks*32 + lg*8];
        f16x8 pfl = *(const f16x8*)&Psl[wave][l15*72 + ks*32 + lg*8];
        #pragma unroll
        for (int dc=0; dc<8; dc++){
          f16x8 vfh = *(const f16x8*)&Vsh[(dc*16 + l15)*72 + ks*32 + lg*8];
          f16x8 vfl = *(const f16x8*)&Vsl[(dc*16 + l15)*72 + ks*32 + lg*8];
          accO[dc] = mfma16h(pfh, vfh, accO[dc]);
          accO[dc] = mfma16h(pfh, vfl, accO[dc]);
          accO[dc] = mfma16h(pfl, vfh, accO[dc]);
        }
      }
    }
    __syncthreads();
  }

  #pragma unroll
  for (int i=0;i<4;i++){
    float inv = 1.0f / (4096.0f * lrun[i]);
    size_t orow = (size_t)(b*S_N + qrow0 + 4*lg + i)*QD_N + h*D_N;
    #pragma unroll
    for (int dc=0; dc<8; dc++){
      u16 hh, ll; split2h(accO[dc][i]*inv, hh, ll);
      aoh[orow + dc*16 + l15] = hh;
      aol[orow + dc*16 + l15] = ll;
    }
  }
}

// ---------------- router
__global__ __launch_bounds__(256) void router_kernel(
    const float* __restrict__ resid2, const float* __restrict__ ln2w,
    const float* __restrict__ gwT, const float* __restrict__ ebias,
    int* __restrict__ tkIdx, float* __restrict__ tkW, int* __restrict__ counts)
{
  int t = blockIdx.x, tid = threadIdx.x;
  __shared__ float xs[H_N];
  __shared__ float red[4];
  __shared__ float sc[E_N];
  const float4* x4 = (const float4*)(resid2 + (size_t)t*H_N);
  float4 a = x4[2*tid], b = x4[2*tid+1];
  float ss = a.x*a.x+a.y*a.y+a.z*a.z+a.w*a.w + b.x*b.x+b.y*b.y+b.z*b.z+b.w*b.w;
  #pragma unroll
  for (int m=32;m>=1;m>>=1) ss += __shfl_xor(ss,m,64);
  if ((tid&63)==0) red[tid>>6]=ss;
  __syncthreads();
  float scale = rsqrtf((red[0]+red[1]+red[2]+red[3])*(1.0f/H_N) + 1e-6f);
  const float4* w4 = (const float4*)ln2w;
  float4 wa = w4[2*tid], wb = w4[2*tid+1];
  xs[tid*8+0]=a.x*scale*wa.x; xs[tid*8+1]=a.y*scale*wa.y;
  xs[tid*8+2]=a.z*scale*wa.z; xs[tid*8+3]=a.w*scale*wa.w;
  xs[tid*8+4]=b.x*scale*wb.x; xs[tid*8+5]=b.y*scale*wb.y;
  xs[tid*8+6]=b.z*scale*wb.z; xs[tid*8+7]=b.w*scale*wb.w;
  __syncthreads();
  int wave = tid>>6, lane = tid&63;
  const float4* xv4 = (const float4*)xs;
  #pragma unroll
  for (int ei=0; ei<8; ei++){
    int e = wave*8 + ei;
    const float4* g4 = (const float4*)(gwT + (size_t)e*H_N);
    float acc = 0.f;
    #pragma unroll
    for (int it=0; it<8; it++){
      int idx = it*64 + lane;
      float4 g = g4[idx], xv = xv4[idx];
      acc += g.x*xv.x + g.y*xv.y + g.z*xv.z + g.w*xv.w;
    }
    #pragma unroll
    for (int m=32;m>=1;m>>=1) acc += __shfl_xor(acc,m,64);
    if (lane==0) sc[e] = 1.0f/(1.0f+__expf(-acc));
  }
  __syncthreads();
  if (tid==0){
    float sb[E_N];
    #pragma unroll
    for (int e2=0;e2<E_N;e2++) sb[e2] = sc[e2]+ebias[e2];
    int ch[4]; float wv[4]; float wsum=0.f;
    for (int j=0;j<4;j++){
      int best=0; float bv=-3.0e38f;
      for (int e2=0;e2<E_N;e2++) if (sb[e2] > bv){ bv=sb[e2]; best=e2; }
      ch[j]=best; wv[j]=sc[best]; wsum+=sc[best]; sb[best]=-3.0e38f;
    }
    float invs = 1.0f/wsum;
    for (int j=0;j<4;j++){
      tkIdx[t*4+j]=ch[j]; tkW[t*4+j]=wv[j]*invs;
      atomicAdd(&counts[ch[j]], 1);
    }
  }
}

// ---------------- deterministic capacity ranking
__global__ void moe_count_kernel(const int* __restrict__ tki, int* __restrict__ G){
  __shared__ int cnt[E_N];
  int g = blockIdx.x, t = threadIdx.x;
  if (t < E_N) cnt[t] = 0;
  __syncthreads();
  atomicAdd(&cnt[tki[g*RGRP + t]], 1);
  __syncthreads();
  if (t < E_N) G[g*E_N + t] = cnt[t];
}

__global__ void moe_scan_kernel(const int* __restrict__ G, int* __restrict__ base,
                                int* __restrict__ starts){
  __shared__ int tot[E_N];
  int e = threadIdx.x;
  if (e < E_N){
    int run = 0;
    for (int g=0; g<NGRP; g++){ base[g*E_N+e] = run; run += G[g*E_N+e]; }
    tot[e] = run < CAP_N ? run : CAP_N;
  }
  __syncthreads();
  if (e==0){
    int run=0;
    for (int x=0; x<E_N; x++){ starts[x]=run; run+=tot[x]; }
  }
}

__global__ void moe_assign_kernel(const int* __restrict__ tki,
                                  const int* __restrict__ base, const int* __restrict__ starts,
                                  int* __restrict__ ptok, int* __restrict__ tok2slot){
  __shared__ int eL[RGRP];
  int g = blockIdx.x, t = threadIdx.x;
  int f = g*RGRP + t;
  int e = tki[f];
  eL[t] = e;
  __syncthreads();
  int r = 0;
  for (int j=0; j<RGRP; j++) r += ((j < t) && (eL[j]==e)) ? 1 : 0;
  int pos = base[g*E_N + e] + r;
  if (pos < CAP_N){
    int slot = starts[e] + pos;
    ptok[slot] = f >> 2;
    tok2slot[f] = slot;
  } else {
    tok2slot[f] = -1;
  }
}

// ---------------- combine
__global__ __launch_bounds__(256) void moe_combine(const int* __restrict__ tok2slot,
                                                   const float* __restrict__ tkw,
                                                   const bf16u* __restrict__ obuf,
                                                   float* __restrict__ outp){
  int t = blockIdx.x;
  int c0 = threadIdx.x*8;
  float acc[8];
  float4* o4 = (float4*)(outp + (size_t)t*H_N + c0);
  float4 v0 = o4[0], v1 = o4[1];
  acc[0]=v0.x; acc[1]=v0.y; acc[2]=v0.z; acc[3]=v0.w;
  acc[4]=v1.x; acc[5]=v1.y; acc[6]=v1.z; acc[7]=v1.w;
  #pragma unroll
  for (int j=0;j<4;j++){
    int slot = tok2slot[t*4+j];
    if (slot >= 0){
      float w = tkw[t*4+j];
      bf16x8 ob = *(const bf16x8*)(obuf + (size_t)slot*H_N + c0);
      #pragma unroll
      for (int q=0;q<8;q++) acc[q] += w * bf2f((bf16u)ob[q]);
    }
  }
  v0.x=acc[0]; v0.y=acc[1]; v0.z=acc[2]; v0.w=acc[3];
  v1.x=acc[4]; v1.y=acc[5]; v1.z=acc[6]; v1.w=acc[7];
  o4[0]=v0; o4[1]=v1;
}

extern "C" void kernel_launch(void* const* d_in, const int* in_sizes, int n_in,
                              void* d_out, int out_size, void* d_ws, size_t ws_size,
                              hipStream_t stream) {
  (void)in_sizes; (void)n_in; (void)out_size; (void)ws_size;
  const float* hidden    = (const float*)d_in[0];
  const int*   positions = (const int*)d_in[1];
  const float* ln1w = (const float*)d_in[2];
  const float* ln2w = (const float*)d_in[3];
  const float* wq   = (const float*)d_in[4];
  const float* wk   = (const float*)d_in[5];
  const float* wv   = (const float*)d_in[6];
  const float* wo   = (const float*)d_in[7];
  const float* qnw  = (const float*)d_in[8];
  const float* knw  = (const float*)d_in[9];
  const float* gatew= (const float*)d_in[10];
  const float* ebias= (const float*)d_in[11];
  const float* wge  = (const float*)d_in[12];
  const float* wue  = (const float*)d_in[13];
  const float* wde  = (const float*)d_in[14];
  const float* wsg  = (const float*)d_in[15];
  const float* wsu  = (const float*)d_in[16];
  const float* wsd  = (const float*)d_in[17];
  float* outp = (float*)d_out;

  char* wsb = (char*)d_ws;
  size_t off = 0;
  auto take = [&](size_t bytes)->char*{
    char* p = wsb + off; off += (bytes + 255) & ~(size_t)255; return p;
  };
  u16* qkvTh = (u16*)take(3072ull*2048*2);
  u16* qkvTl = (u16*)take(3072ull*2048*2);
  u16* woTh = (u16*)take(2048ull*2048*2);
  u16* woTl = (u16*)take(2048ull*2048*2);
  u16* wsgT = (u16*)take(1024ull*2048*2);
  u16* wsuT = (u16*)take(1024ull*2048*2);
  u16* wsdT = (u16*)take(2048ull*1024*2);
  u16* wgeT = (u16*)take(32ull*512*2048*2);
  u16* wueT = (u16*)take(32ull*512*2048*2);
  u16* wdeT = (u16*)take(32ull*2048*512*2);
  float* gwT = (float*)take(32ull*2048*4);
  u16* h1h  = (u16*)take((size_t)T_N*H_N*2);
  u16* h1l  = (u16*)take((size_t)T_N*H_N*2);
  float* qkv32 = (float*)take((size_t)T_N*QKV_N*4);
  u16* qHh  = (u16*)take((size_t)T_N*QD_N*2);
  u16* qHl  = (u16*)take((size_t)T_N*QD_N*2);
  u16* kHh  = (u16*)take((size_t)T_N*KD_N*2);
  u16* kHl  = (u16*)take((size_t)T_N*KD_N*2);
  u16* vtHh = (u16*)take((size_t)T_N*KD_N*2);
  u16* vtHl = (u16*)take((size_t)T_N*KD_N*2);
  u16* aoh  = (u16*)take((size_t)T_N*QD_N*2);
  u16* aol  = (u16*)take((size_t)T_N*QD_N*2);
  float* resid2=(float*)take((size_t)T_N*H_N*4);
  u16* h2   = (u16*)take((size_t)T_N*H_N*2);
  u16* interS=(u16*)take((size_t)T_N*SIM_N*2);
  u16* minter=(u16*)take((size_t)NFLAT*IM_N*2);
  bf16u* obuf = (bf16u*)take((size_t)NFLAT*H_N*2);
  int*   tki  = (int*)take((size_t)NFLAT*4);
  float* tkw  = (float*)take((size_t)NFLAT*4);
  int*   counts=(int*)take(E_N*4);
  int*   Gcnt = (int*)take((size_t)NGRP*E_N*4);
  int*   Gbase= (int*)take((size_t)NGRP*E_N*4);
  int*   starts=(int*)take(E_N*4);
  int*   ptok = (int*)take((size_t)NFLAT*4);
  int*   tok2slot = (int*)take((size_t)NFLAT*4);

  hipMemsetAsync(counts, 0, 256, stream);

  dim3 tb(32,8);
  transpose_split16_g<<<dim3(32,32), 256, 0, stream>>>(wq, qkvTh, qkvTl, 2048, 2048, SC_W);
  transpose_split16_g<<<dim3(32,8),  256, 0, stream>>>(wk, qkvTh + 2048ull*2048, qkvTl + 2048ull*2048, 2048, 512, SC_W);
  transpose_split16_g<<<dim3(32,8),  256, 0, stream>>>(wv, qkvTh + 2560ull*2048, qkvTl + 2560ull*2048, 2048, 512, SC_W);
  transpose_split16_g<<<dim3(32,32), 256, 0, stream>>>(wo, woTh, woTl, 2048, 2048, SC_W);
  transpose_cvt_g<<<dim3(32,16,1), 256, 0, stream>>>(wsg, wsgT, 2048, 1024);
  transpose_cvt_g<<<dim3(32,16,1), 256, 0, stream>>>(wsu, wsuT, 2048, 1024);
  transpose_cvt_g<<<dim3(16,32,1), 256, 0, stream>>>(wsd, wsdT, 1024, 2048);
  transpose_cvt_g<<<dim3(32,8,32), 256, 0, stream>>>(wge, wgeT, 2048, 512);
  transpose_cvt_g<<<dim3(32,8,32), 256, 0, stream>>>(wue, wueT, 2048, 512);
  transpose_cvt_g<<<dim3(8,32,32), 256, 0, stream>>>(wde, wdeT, 512, 2048);
  transpose_f32<<<dim3(64,1,1), tb, 0, stream>>>(gatew, gwT, 2048, 32);

  rmsnorm_f16split<<<T_N, 256, 0, stream>>>(hidden, ln1w, h1h, h1l);
  gemm_split64<<<dim3(16,24), 256, 0, stream>>>(h1h, h1l, qkvTh, qkvTl, qkv32, nullptr, OSC_QKV, QKV_N, H_N);
  qknorm_rope_split<<<dim3(T_N,20), 64, 0, stream>>>(qkv32, qnw, knw, positions, qHh, qHl, kHh, kHl);
  transpose_v_split<<<dim3(32,4,8), tb, 0, stream>>>(qkv32, vtHh, vtHl);
  attn_kernel<<<dim3(8,32), 512, 0, stream>>>(qHh, qHl, kHh, kHl, vtHh, vtHl, aoh, aol);
  gemm_split64<<<dim3(16,16), 256, 0, stream>>>(aoh, aol, woTh, woTl, resid2, hidden, OSC_OPJ, H_N, QD_N);
  rmsnorm_bf16<<<T_N, 256, 0, stream>>>(resid2, ln2w, (bf16u*)h2);
  gemm_bt8<2><<<dim3(16,8), 512, 0, stream>>>(h2, wsgT, wsuT, interS, nullptr, 1.0f, SIM_N, H_N);
  gemm_bt8<1><<<dim3(16,16), 512, 0, stream>>>(interS, wsdT, nullptr, outp, resid2, 1.0f, H_N, SIM_N);
  router_kernel<<<T_N, 256, 0, stream>>>(resid2, ln2w, gwT, ebias, tki, tkw, counts);
  moe_count_kernel<<<NGRP, RGRP, 0, stream>>>(tki, Gcnt);
  moe_scan_kernel<<<1, 64, 0, stream>>>(Gcnt, Gbase, starts);
  moe_assign_kernel<<<NGRP, RGRP, 0, stream>>>(tki, Gbase, starts, ptok, tok2slot);
  moe_gu8w<<<dim3(4,4,32), 512, 0, stream>>>(h2, wgeT, wueT, minter, starts, counts, ptok);
  moe_down8w<<<dim3(4,16,32), 512, 0, stream>>>(minter, wdeT, obuf, starts, counts);
  moe_combine<<<T_N, 256, 0, stream>>>(tok2slot, tkw, obuf, outp);
}

// Round 16
// 784.589 us; speedup vs baseline: 1.0371x; 1.0371x over previous
//
#include <hip/hip_runtime.h>
#include <stdint.h>

typedef unsigned short u16;
typedef unsigned short bf16u;
typedef unsigned int u32;
typedef _Float16 f16;
typedef __attribute__((ext_vector_type(8))) short bf16x8;
typedef __attribute__((ext_vector_type(8))) _Float16 f16x8;
typedef __attribute__((ext_vector_type(4))) float f32x4;

#define T_N 2048
#define H_N 2048
#define S_N 1024
#define B_N 2
#define HQ_N 16
#define HKV_N 4
#define D_N 128
#define E_N 32
#define K_TOP 4
#define CAP_N 512
#define IM_N 512
#define SIM_N 1024
#define QD_N 2048
#define KD_N 512
#define QKV_N 3072
#define NFLAT (T_N*K_TOP)
#define RGRP 128
#define NGRP (NFLAT/RGRP)

#define SC_H1   1024.0f
#define SC_W    512.0f
#define SC_QK   2048.0f
#define SC_P    4096.0f
#define SC_V    2048.0f
#define OSC_QKV (1.0f/524288.0f)
#define OSC_OPJ (1.0f/1048576.0f)

__device__ __forceinline__ float bf2f(bf16u x){ return __uint_as_float(((u32)x)<<16); }
__device__ __forceinline__ bf16u f2bf(float f){
  u32 u = __float_as_uint(f);
  u32 r = (u + 0x7FFFu + ((u>>16)&1u)) >> 16;
  return (bf16u)r;
}
__device__ __forceinline__ u32 pkbf(float a, float b){
  u32 ua = __float_as_uint(a), ub = __float_as_uint(b);
  u32 ra = (ua + 0x7FFFu + ((ua>>16)&1u)) >> 16;
  u32 rb = (ub + 0x7FFFu + ((ub>>16)&1u)) & 0xFFFF0000u;
  return ra | rb;
}
__device__ __forceinline__ void split2h(float x, u16& h, u16& l){
  f16 hh = (f16)x;
  f16 ll = (f16)(x - (float)hh);
  h = __builtin_bit_cast(u16, hh);
  l = __builtin_bit_cast(u16, ll);
}
__device__ __forceinline__ f32x4 mfma16b(bf16x8 a, bf16x8 b, f32x4 c){
  return __builtin_amdgcn_mfma_f32_16x16x32_bf16(a,b,c,0,0,0);
}
__device__ __forceinline__ f32x4 mfma16h(f16x8 a, f16x8 b, f32x4 c){
  return __builtin_amdgcn_mfma_f32_16x16x32_f16(a,b,c,0,0,0);
}
__device__ __forceinline__ void gl_lds16(const void* g, void* l){
  __builtin_amdgcn_global_load_lds((const __attribute__((address_space(1))) u32*)g,
                                   (__attribute__((address_space(3))) u32*)l, 16, 0, 0);
}
template<int N> __device__ __forceinline__ void waitv(){
  if constexpr (N==0) asm volatile("s_waitcnt vmcnt(0)" ::: "memory");
  else if constexpr (N==2) asm volatile("s_waitcnt vmcnt(2)" ::: "memory");
  else if constexpr (N==3) asm volatile("s_waitcnt vmcnt(3)" ::: "memory");
  else if constexpr (N==4) asm volatile("s_waitcnt vmcnt(4)" ::: "memory");
  __builtin_amdgcn_sched_barrier(0);
}
__device__ __forceinline__ int xcd_swz(int lin, int nwg){
  int cpx = nwg >> 3;
  return (lin & 7)*cpx + (lin >> 3);
}

// ---------------- fp32 transpose (gate_w only, C=32)
__global__ __launch_bounds__(256) void transpose_f32(const float* __restrict__ in,
                                                     float* __restrict__ out, int R, int C){
  __shared__ float tile[32][33];
  int rb = blockIdx.x*32, cb = blockIdx.y*32;
  int tx = threadIdx.x, ty = threadIdx.y;
  #pragma unroll
  for (int kk=0;kk<4;kk++)
    tile[ty+kk*8][tx] = in[(size_t)(rb+ty+kk*8)*C + cb + tx];
  __syncthreads();
  #pragma unroll
  for (int kk=0;kk<4;kk++)
    out[(size_t)(cb+ty+kk*8)*R + rb + tx] = tile[tx][ty+kk*8];
}

// ---------------- fast transpose + fp32->bf16
__global__ __launch_bounds__(256) void transpose_cvt_g(const float* __restrict__ in,
                                                       bf16u* __restrict__ out, int R, int C){
  __shared__ float tile[64*64];
  size_t zo = (size_t)blockIdx.z * R * C;
  int rb = blockIdx.x*64, cb = blockIdx.y*64;
  int tid = threadIdx.x, wave = tid>>6, lane = tid&63;
  #pragma unroll
  for (int p=0;p<4;p++){
    int r = p*16 + wave*4 + (lane>>4);
    const float* src = in + zo + (size_t)(rb + r)*C + cb + (lane&15)*4;
    gl_lds16(src, &tile[(p*16 + wave*4)*64]);
  }
  __syncthreads();
  int c = tid>>2, rq = (tid&3)*16;
  u16 tmp[16];
  #pragma unroll
  for (int j=0;j<16;j++) tmp[j] = f2bf(tile[(rq+j)*64 + c]);
  uint4 w0, w1;
  w0.x=(u32)tmp[0]|((u32)tmp[1]<<16);  w0.y=(u32)tmp[2]|((u32)tmp[3]<<16);
  w0.z=(u32)tmp[4]|((u32)tmp[5]<<16);  w0.w=(u32)tmp[6]|((u32)tmp[7]<<16);
  w1.x=(u32)tmp[8]|((u32)tmp[9]<<16);  w1.y=(u32)tmp[10]|((u32)tmp[11]<<16);
  w1.z=(u32)tmp[12]|((u32)tmp[13]<<16); w1.w=(u32)tmp[14]|((u32)tmp[15]<<16);
  bf16u* dst = out + zo + (size_t)(cb+c)*R + rb + rq;
  *(uint4*)dst = w0;
  *(uint4*)(dst+8) = w1;
}

// ---------------- fast transpose + f16 split (scaled)
__global__ __launch_bounds__(256) void transpose_split16_g(const float* __restrict__ in,
                                                           u16* __restrict__ oh,
                                                           u16* __restrict__ ol,
                                                           int R, int C, float scale){
  __shared__ float tile[64*64];
  int rb = blockIdx.x*64, cb = blockIdx.y*64;
  int tid = threadIdx.x, wave = tid>>6, lane = tid&63;
  #pragma unroll
  for (int p=0;p<4;p++){
    int r = p*16 + wave*4 + (lane>>4);
    const float* src = in + (size_t)(rb + r)*C + cb + (lane&15)*4;
    gl_lds16(src, &tile[(p*16 + wave*4)*64]);
  }
  __syncthreads();
  int c = tid>>2, rq = (tid&3)*16;
  u16 th[16], tl[16];
  #pragma unroll
  for (int j=0;j<16;j++) split2h(tile[(rq+j)*64 + c]*scale, th[j], tl[j]);
  uint4 h0, h1, l0, l1;
  h0.x=(u32)th[0]|((u32)th[1]<<16);  h0.y=(u32)th[2]|((u32)th[3]<<16);
  h0.z=(u32)th[4]|((u32)th[5]<<16);  h0.w=(u32)th[6]|((u32)th[7]<<16);
  h1.x=(u32)th[8]|((u32)th[9]<<16);  h1.y=(u32)th[10]|((u32)th[11]<<16);
  h1.z=(u32)th[12]|((u32)th[13]<<16); h1.w=(u32)th[14]|((u32)th[15]<<16);
  l0.x=(u32)tl[0]|((u32)tl[1]<<16);  l0.y=(u32)tl[2]|((u32)tl[3]<<16);
  l0.z=(u32)tl[4]|((u32)tl[5]<<16);  l0.w=(u32)tl[6]|((u32)tl[7]<<16);
  l1.x=(u32)tl[8]|((u32)tl[9]<<16);  l1.y=(u32)tl[10]|((u32)tl[11]<<16);
  l1.z=(u32)tl[12]|((u32)tl[13]<<16); l1.w=(u32)tl[14]|((u32)tl[15]<<16);
  size_t o = (size_t)(cb+c)*R + rb + rq;
  *(uint4*)(oh + o) = h0; *(uint4*)(oh + o + 8) = h1;
  *(uint4*)(ol + o) = l0; *(uint4*)(ol + o + 8) = l1;
}

// ---------------- RMSNorm fp32 -> bf16
__global__ __launch_bounds__(256) void rmsnorm_bf16(const float* __restrict__ x,
                                                    const float* __restrict__ w,
                                                    bf16u* __restrict__ y){
  int row = blockIdx.x; int t = threadIdx.x;
  const float4* x4 = (const float4*)(x + (size_t)row*H_N);
  float4 a = x4[2*t], b = x4[2*t+1];
  float ss = a.x*a.x+a.y*a.y+a.z*a.z+a.w*a.w + b.x*b.x+b.y*b.y+b.z*b.z+b.w*b.w;
  #pragma unroll
  for (int m=32;m>=1;m>>=1) ss += __shfl_xor(ss,m,64);
  __shared__ float red[4];
  if ((t&63)==0) red[t>>6]=ss;
  __syncthreads();
  float scale = rsqrtf((red[0]+red[1]+red[2]+red[3])*(1.0f/H_N) + 1e-6f);
  const float4* w4 = (const float4*)w;
  float4 wa = w4[2*t], wb = w4[2*t+1];
  uint4 pk;
  pk.x = pkbf(a.x*scale*wa.x, a.y*scale*wa.y);
  pk.y = pkbf(a.z*scale*wa.z, a.w*scale*wa.w);
  pk.z = pkbf(b.x*scale*wb.x, b.y*scale*wb.y);
  pk.w = pkbf(b.z*scale*wb.z, b.w*scale*wb.w);
  ((uint4*)(y + (size_t)row*H_N))[t] = pk;
}

// ---------------- RMSNorm fp32 -> f16 split (scaled)
__global__ __launch_bounds__(256) void rmsnorm_f16split(const float* __restrict__ x,
                                                        const float* __restrict__ w,
                                                        u16* __restrict__ yh,
                                                        u16* __restrict__ yl){
  int row = blockIdx.x; int t = threadIdx.x;
  const float4* x4 = (const float4*)(x + (size_t)row*H_N);
  float4 a = x4[2*t], b = x4[2*t+1];
  float ss = a.x*a.x+a.y*a.y+a.z*a.z+a.w*a.w + b.x*b.x+b.y*b.y+b.z*b.z+b.w*b.w;
  #pragma unroll
  for (int m=32;m>=1;m>>=1) ss += __shfl_xor(ss,m,64);
  __shared__ float red[4];
  if ((t&63)==0) red[t>>6]=ss;
  __syncthreads();
  float scale = rsqrtf((red[0]+red[1]+red[2]+red[3])*(1.0f/H_N) + 1e-6f) * SC_H1;
  const float4* w4 = (const float4*)w;
  float4 wa = w4[2*t], wb = w4[2*t+1];
  float o[8] = {a.x*scale*wa.x, a.y*scale*wa.y, a.z*scale*wa.z, a.w*scale*wa.w,
                b.x*scale*wb.x, b.y*scale*wb.y, b.z*scale*wb.z, b.w*scale*wb.w};
  u16 hh[8], ll[8];
  #pragma unroll
  for (int j=0;j<8;j++) split2h(o[j], hh[j], ll[j]);
  uint4 pk, pl;
  pk.x = (u32)hh[0]|((u32)hh[1]<<16); pk.y = (u32)hh[2]|((u32)hh[3]<<16);
  pk.z = (u32)hh[4]|((u32)hh[5]<<16); pk.w = (u32)hh[6]|((u32)hh[7]<<16);
  pl.x = (u32)ll[0]|((u32)ll[1]<<16); pl.y = (u32)ll[2]|((u32)ll[3]<<16);
  pl.z = (u32)ll[4]|((u32)ll[5]<<16); pl.w = (u32)ll[6]|((u32)ll[7]<<16);
  ((uint4*)(yh + (size_t)row*H_N))[t] = pk;
  ((uint4*)(yl + (size_t)row*H_N))[t] = pl;
}

// ---------------- qk-norm + neox RoPE (fp64 trig)
__global__ void qknorm_rope_split(const float* __restrict__ qkv,
                                  const float* __restrict__ qw, const float* __restrict__ kw,
                                  const int* __restrict__ positions,
                                  u16* __restrict__ qho, u16* __restrict__ qlo,
                                  u16* __restrict__ kho, u16* __restrict__ klo){
  int t = blockIdx.x; int hy = blockIdx.y; int l = threadIdx.x;
  const float* p; const float* w; u16 *oh, *ol; size_t obase;
  if (hy < HQ_N){
    p = qkv + (size_t)t*QKV_N + hy*D_N; w = qw;
    oh = qho; ol = qlo; obase = (size_t)t*QD_N + hy*D_N;
  } else {
    p = qkv + (size_t)t*QKV_N + QD_N + (hy-HQ_N)*D_N; w = kw;
    oh = kho; ol = klo; obase = (size_t)t*KD_N + (hy-HQ_N)*D_N;
  }
  float x0 = p[l], x1 = p[l+64];
  float ss = x0*x0 + x1*x1;
  #pragma unroll
  for (int m=32;m>=1;m>>=1) ss += __shfl_xor(ss,m,64);
  float scale = rsqrtf(ss*(1.0f/D_N)+1e-6f);
  x0 *= scale*w[l]; x1 *= scale*w[l+64];
  double freq = exp2(-(double)l * (19.931568569324174/64.0));
  double fr = (double)positions[t] * freq;
  double sd, cd; sincos(fr, &sd, &cd);
  float r0 = (float)((double)x0*cd - (double)x1*sd) * SC_QK;
  float r1 = (float)((double)x1*cd + (double)x0*sd) * SC_QK;
  u16 hh, ll;
  split2h(r0, hh, ll); oh[obase+l] = hh; ol[obase+l] = ll;
  split2h(r1, hh, ll); oh[obase+l+64] = hh; ol[obase+l+64] = ll;
}

// ---------------- V transpose + f16 split (scaled)
__global__ __launch_bounds__(256) void transpose_v_split(const float* __restrict__ in,
                                                         u16* __restrict__ oh,
                                                         u16* __restrict__ ol){
  __shared__ u16 th[32][33];
  __shared__ u16 tl[32][33];
  int z = blockIdx.z; int b = z >> 2, kvh = z & 3;
  const float* ip = in + (size_t)b*S_N*QKV_N + QD_N + KD_N + kvh*D_N;
  size_t ob = (size_t)z*D_N*S_N;
  int sb = blockIdx.x*32, db = blockIdx.y*32;
  int tx=threadIdx.x, ty=threadIdx.y;
  #pragma unroll
  for (int kk=0;kk<4;kk++){
    float x = ip[(size_t)(sb+ty+kk*8)*QKV_N + db+tx] * SC_V;
    u16 hh, ll; split2h(x, hh, ll);
    th[ty+kk*8][tx] = hh; tl[ty+kk*8][tx] = ll;
  }
  __syncthreads();
  #pragma unroll
  for (int kk=0;kk<4;kk++){
    size_t idx = ob + (size_t)(db+ty+kk*8)*S_N + sb+tx;
    oh[idx] = th[tx][ty+kk*8];
    ol[idx] = tl[tx][ty+kk*8];
  }
}

// ---------------- dense GEMM, 8-wave 512thr, XCD+LDS swizzle, counted-vmcnt
// MODE 1: f32 out*oscale (+resid). MODE 2: silu(g)*u bf16 (dual B).
// LDS bank-conflict fix: chunk' = chunk ^ ((row>>1)&3), applied to global SOURCE
// (staging col) and LDS fragment READ (same involution).
template<int MODE, bool SPLIT>
__global__ __launch_bounds__(512) void gemm_bt8(
    const u16* __restrict__ A, const u16* __restrict__ Al,
    const u16* __restrict__ B0g, const u16* __restrict__ B0lg,
    const u16* __restrict__ B1g,
    void* __restrict__ Cout, const float* __restrict__ resid, float oscale,
    int N, int Kd)
{
  constexpr bool DUAL = (MODE==2);
  constexpr int LD = SPLIT ? 4 : (DUAL ? 3 : 2);
  __shared__ u16 As[2][128*32];
  __shared__ u16 Bs0[2][128*32];
  __shared__ u16 Asl[SPLIT?2:1][SPLIT?128*32:8];
  __shared__ u16 Bs0l[SPLIT?2:1][SPLIT?128*32:8];
  __shared__ u16 Bs1[DUAL?2:1][DUAL?128*32:8];

  int tid = threadIdx.x;
  int wave = tid>>6, lane = tid&63, l15 = lane&15, lg = lane>>4;
  int sw = (l15>>1)&3;
  int nwgx = gridDim.x;
  int lin = blockIdx.y*nwgx + blockIdx.x;
  int swz = xcd_swz(lin, nwgx*gridDim.y);
  int mBase = (swz % nwgx)*128;
  int nBase = (swz / nwgx)*128;

  int r = tid>>2;
  int c = (((tid&3) ^ ((r>>1)&3)))*8;
  size_t aOff = (size_t)(mBase + r)*Kd + c;
  size_t bOff = (size_t)(nBase + r)*Kd + c;

  auto STAGE = [&](int buf, int kt){
    size_t ko = (size_t)kt*32;
    gl_lds16(A + aOff + ko, &As[buf][tid*8]);
    gl_lds16(B0g + bOff + ko, &Bs0[buf][tid*8]);
    if constexpr (SPLIT){
      gl_lds16(Al + aOff + ko, &Asl[buf][tid*8]);
      gl_lds16(B0lg + bOff + ko, &Bs0l[buf][tid*8]);
    }
    if constexpr (DUAL){
      gl_lds16(B1g + bOff + ko, &Bs1[buf][tid*8]);
    }
  };

  f32x4 zero4 = {0.f,0.f,0.f,0.f};
  f32x4 acc0[2][4];
  f32x4 acc1[DUAL?2:1][DUAL?4:1];
  #pragma unroll
  for (int mi=0;mi<2;mi++)
    #pragma unroll
    for (int ni=0;ni<4;ni++){
      acc0[mi][ni] = zero4;
      if constexpr (DUAL) acc1[mi][ni] = zero4;
    }

  int wm = wave>>1, wn = wave&1;
  int kread = ((lg ^ sw))*8;
  int nK = Kd >> 5;
  STAGE(0, 0);
  for (int kt=0; kt<nK; kt++){
    int cur = kt&1;
    if (kt+1 < nK){ STAGE(cur^1, kt+1); waitv<LD>(); }
    else waitv<0>();
    __builtin_amdgcn_s_barrier();
    __builtin_amdgcn_sched_barrier(0);
    if constexpr (SPLIT){
      f16x8 af[2], afl[2];
      #pragma unroll
      for (int mi=0;mi<2;mi++){
        af[mi]  = *(const f16x8*)&As [cur][(wm*32 + mi*16 + l15)*32 + kread];
        afl[mi] = *(const f16x8*)&Asl[cur][(wm*32 + mi*16 + l15)*32 + kread];
      }
      __builtin_amdgcn_s_setprio(1);
      #pragma unroll
      for (int ni=0;ni<4;ni++){
        f16x8 b0  = *(const f16x8*)&Bs0 [cur][(wn*64 + ni*16 + l15)*32 + kread];
        f16x8 b0l = *(const f16x8*)&Bs0l[cur][(wn*64 + ni*16 + l15)*32 + kread];
        #pragma unroll
        for (int mi=0;mi<2;mi++){
          acc0[mi][ni] = mfma16h(af[mi], b0, acc0[mi][ni]);
          acc0[mi][ni] = mfma16h(af[mi], b0l, acc0[mi][ni]);
          acc0[mi][ni] = mfma16h(afl[mi], b0, acc0[mi][ni]);
        }
      }
      __builtin_amdgcn_s_setprio(0);
    } else {
      bf16x8 af[2];
      #pragma unroll
      for (int mi=0;mi<2;mi++)
        af[mi] = *(const bf16x8*)&As[cur][(wm*32 + mi*16 + l15)*32 + kread];
      __builtin_amdgcn_s_setprio(1);
      #pragma unroll
      for (int ni=0;ni<4;ni++){
        bf16x8 b0 = *(const bf16x8*)&Bs0[cur][(wn*64 + ni*16 + l15)*32 + kread];
        #pragma unroll
        for (int mi=0;mi<2;mi++) acc0[mi][ni] = mfma16b(af[mi], b0, acc0[mi][ni]);
        if constexpr (DUAL){
          bf16x8 b1 = *(const bf16x8*)&Bs1[cur][(wn*64 + ni*16 + l15)*32 + kread];
          #pragma unroll
          for (int mi=0;mi<2;mi++) acc1[mi][ni] = mfma16b(af[mi], b1, acc1[mi][ni]);
        }
      }
      __builtin_amdgcn_s_setprio(0);
    }
    asm volatile("s_waitcnt lgkmcnt(0)" ::: "memory");
    __builtin_amdgcn_sched_barrier(0);
    __builtin_amdgcn_s_barrier();
  }

  #pragma unroll
  for (int mi=0;mi<2;mi++){
    #pragma unroll
    for (int ni=0;ni<4;ni++){
      #pragma unroll
      for (int i=0;i<4;i++){
        int rloc = wm*32 + mi*16 + 4*lg + i;
        int col  = nBase + wn*64 + ni*16 + l15;
        float v = acc0[mi][ni][i];
        if constexpr (MODE==1){
          size_t idx = (size_t)(mBase + rloc)*N + col;
          ((float*)Cout)[idx] = v*oscale + (resid ? resid[idx] : 0.0f);
        } else {
          float u = acc1[mi][ni][i];
          float sv = v/(1.0f+__expf(-v))*u;
          ((bf16u*)Cout)[(size_t)(mBase + rloc)*N + col] = f2bf(sv);
        }
      }
    }
  }
}

// ---------------- MoE gate/up: counted-vmcnt, 8 waves, XCD+LDS swizzle
__global__ __launch_bounds__(512) void moe_gu8w(
    const u16* __restrict__ A,
    const u16* __restrict__ B0g,
    const u16* __restrict__ B1g,
    bf16u* __restrict__ Out,
    const int* __restrict__ starts, const int* __restrict__ counts,
    const int* __restrict__ perm)
{
  __shared__ u16 As[2][128*32];
  __shared__ u16 Bs0[2][128*32];
  __shared__ u16 Bs1[2][128*32];

  int nwgx = gridDim.x, nwgy = gridDim.y;
  int lin = (blockIdx.z*nwgy + blockIdx.y)*nwgx + blockIdx.x;
  int swzi = xcd_swz(lin, nwgx*nwgy*gridDim.z);
  int bx = swzi % nwgx; swzi /= nwgx;
  int by = swzi % nwgy;
  int e  = swzi / nwgy;

  int cnt = counts[e]; cnt = cnt < CAP_N ? cnt : CAP_N;
  int mBase = bx*128;
  int rows = cnt - mBase;
  if (rows <= 0) return;
  if (rows > 128) rows = 128;
  int slotBase = starts[e] + mBase;
  int nBase = by*128;
  const u16* Bp0 = B0g + (size_t)e*IM_N*H_N;
  const u16* Bp1 = B1g + (size_t)e*IM_N*H_N;

  int tid = threadIdx.x, wave = tid>>6, lane = tid&63, l15 = lane&15, lg = lane>>4;
  int sw = (l15>>1)&3;
  int r = tid>>2;
  int c = (((tid&3) ^ ((r>>1)&3)))*8;
  int rr = (r < rows) ? r : 0;
  size_t aOff = (size_t)perm[slotBase + rr]*H_N + c;
  size_t bOff = (size_t)(nBase + r)*H_N + c;

  auto STAGE = [&](int buf, int kt){
    size_t ko = (size_t)kt*32;
    gl_lds16(A + aOff + ko, &As[buf][tid*8]);
    gl_lds16(Bp0 + bOff + ko, &Bs0[buf][tid*8]);
    gl_lds16(Bp1 + bOff + ko, &Bs1[buf][tid*8]);
  };

  f32x4 zero4 = {0.f,0.f,0.f,0.f};
  f32x4 acc0[2][4], acc1[2][4];
  #pragma unroll
  for (int mi=0;mi<2;mi++)
    #pragma unroll
    for (int ni=0;ni<4;ni++){ acc0[mi][ni]=zero4; acc1[mi][ni]=zero4; }

  int wm = wave>>1, wn = wave&1;
  int kread = ((lg ^ sw))*8;
  STAGE(0, 0);
  int nK = H_N >> 5;
  for (int kt=0; kt<nK; kt++){
    int cur = kt&1;
    if (kt+1 < nK){ STAGE(cur^1, kt+1); waitv<3>(); }
    else waitv<0>();
    __builtin_amdgcn_s_barrier();
    __builtin_amdgcn_sched_barrier(0);
    bf16x8 af[2];
    #pragma unroll
    for (int mi=0;mi<2;mi++)
      af[mi] = *(const bf16x8*)&As[cur][(wm*32 + mi*16 + l15)*32 + kread];
    __builtin_amdgcn_s_setprio(1);
    #pragma unroll
    for (int ni=0;ni<4;ni++){
      bf16x8 b0 = *(const bf16x8*)&Bs0[cur][(wn*64 + ni*16 + l15)*32 + kread];
      bf16x8 b1 = *(const bf16x8*)&Bs1[cur][(wn*64 + ni*16 + l15)*32 + kread];
      #pragma unroll
      for (int mi=0;mi<2;mi++){
        acc0[mi][ni] = mfma16b(af[mi], b0, acc0[mi][ni]);
        acc1[mi][ni] = mfma16b(af[mi], b1, acc1[mi][ni]);
      }
    }
    __builtin_amdgcn_s_setprio(0);
    asm volatile("s_waitcnt lgkmcnt(0)" ::: "memory");
    __builtin_amdgcn_sched_barrier(0);
    __builtin_amdgcn_s_barrier();
  }

  #pragma unroll
  for (int mi=0;mi<2;mi++){
    #pragma unroll
    for (int ni=0;ni<4;ni++){
      #pragma unroll
      for (int i=0;i<4;i++){
        int rloc = wm*32 + mi*16 + 4*lg + i;
        if (rloc < rows){
          float v = acc0[mi][ni][i];
          float u = acc1[mi][ni][i];
          float sv = v/(1.0f+__expf(-v))*u;
          Out[(size_t)(slotBase + rloc)*IM_N + nBase + wn*64 + ni*16 + l15] = f2bf(sv);
        }
      }
    }
  }
}

// ---------------- MoE down: counted-vmcnt, 8 waves, XCD+LDS swizzle
__global__ __launch_bounds__(512) void moe_down8w(
    const u16* __restrict__ A,
    const u16* __restrict__ B0g,
    bf16u* __restrict__ Out,
    const int* __restrict__ starts, const int* __restrict__ counts)
{
  __shared__ u16 As[2][128*32];
  __shared__ u16 Bs0[2][128*32];

  int nwgx = gridDim.x, nwgy = gridDim.y;
  int lin = (blockIdx.z*nwgy + blockIdx.y)*nwgx + blockIdx.x;
  int swzi = xcd_swz(lin, nwgx*nwgy*gridDim.z);
  int bx = swzi % nwgx; swzi /= nwgx;
  int by = swzi % nwgy;
  int e  = swzi / nwgy;

  int cnt = counts[e]; cnt = cnt < CAP_N ? cnt : CAP_N;
  int mBase = bx*128;
  int rows = cnt - mBase;
  if (rows <= 0) return;
  if (rows > 128) rows = 128;
  int slotBase = starts[e] + mBase;
  int nBase = by*128;
  const u16* Bp0 = B0g + (size_t)e*H_N*IM_N;

  int tid = threadIdx.x, wave = tid>>6, lane = tid&63, l15 = lane&15, lg = lane>>4;
  int sw = (l15>>1)&3;
  int r = tid>>2;
  int c = (((tid&3) ^ ((r>>1)&3)))*8;
  int rr = (r < rows) ? r : 0;
  size_t aOff = (size_t)(slotBase + rr)*IM_N + c;
  size_t bOff = (size_t)(nBase + r)*IM_N + c;

  auto STAGE = [&](int buf, int kt){
    size_t ko = (size_t)kt*32;
    gl_lds16(A + aOff + ko, &As[buf][tid*8]);
    gl_lds16(Bp0 + bOff + ko, &Bs0[buf][tid*8]);
  };

  f32x4 zero4 = {0.f,0.f,0.f,0.f};
  f32x4 acc0[2][4];
  #pragma unroll
  for (int mi=0;mi<2;mi++)
    #pragma unroll
    for (int ni=0;ni<4;ni++) acc0[mi][ni]=zero4;

  int wm = wave>>1, wn = wave&1;
  int kread = ((lg ^ sw))*8;
  STAGE(0, 0);
  int nK = IM_N >> 5;
  for (int kt=0; kt<nK; kt++){
    int cur = kt&1;
    if (kt+1 < nK){ STAGE(cur^1, kt+1); waitv<2>(); }
    else waitv<0>();
    __builtin_amdgcn_s_barrier();
    __builtin_amdgcn_sched_barrier(0);
    bf16x8 af[2];
    #pragma unroll
    for (int mi=0;mi<2;mi++)
      af[mi] = *(const bf16x8*)&As[cur][(wm*32 + mi*16 + l15)*32 + kread];
    __builtin_amdgcn_s_setprio(1);
    #pragma unroll
    for (int ni=0;ni<4;ni++){
      bf16x8 b0 = *(const bf16x8*)&Bs0[cur][(wn*64 + ni*16 + l15)*32 + kread];
      #pragma unroll
      for (int mi=0;mi<2;mi++)
        acc0[mi][ni] = mfma16b(af[mi], b0, acc0[mi][ni]);
    }
    __builtin_amdgcn_s_setprio(0);
    asm volatile("s_waitcnt lgkmcnt(0)" ::: "memory");
    __builtin_amdgcn_sched_barrier(0);
    __builtin_amdgcn_s_barrier();
  }

  #pragma unroll
  for (int mi=0;mi<2;mi++){
    #pragma unroll
    for (int ni=0;ni<4;ni++){
      #pragma unroll
      for (int i=0;i<4;i++){
        int rloc = wm*32 + mi*16 + 4*lg + i;
        if (rloc < rows)
          Out[(size_t)(slotBase + rloc)*H_N + nBase + wn*64 + ni*16 + l15] = f2bf(acc0[mi][ni][i]);
      }
    }
  }
}

// ---------------- flash attention, causal GQA, f16 split, 8-wave paired q-tiles
__global__ __launch_bounds__(512) void attn_kernel(
    const u16* __restrict__ qh, const u16* __restrict__ ql,
    const u16* __restrict__ kh, const u16* __restrict__ kl,
    const u16* __restrict__ vth, const u16* __restrict__ vtl,
    u16* __restrict__ aoh, u16* __restrict__ aol)
{
  int bx = blockIdx.x;
  int bh = blockIdx.y;
  int b = bh >> 4, h = bh & 15, kvh = h >> 2;
  int tid = threadIdx.x, wave = tid>>6, lane = tid&63, l15 = lane&15, lg = lane>>4;

  __shared__ u16 Ksh[64*136];
  __shared__ u16 Ksl[64*136];
  __shared__ u16 Vsh[128*72];
  __shared__ u16 Vsl[128*72];
  __shared__ u16 Psh[8][16*72];
  __shared__ u16 Psl[8][16*72];

  int qtile = (wave < 4) ? bx : (15 - bx);
  int wl = wave & 3;
  int qrow0 = qtile*64 + wl*16;

  size_t qrow = (size_t)(b*S_N + qrow0 + l15)*QD_N + h*D_N;
  f16x8 qfh[4], qfl[4];
  #pragma unroll
  for (int ds=0; ds<4; ds++){
    qfh[ds] = *(const f16x8*)(qh + qrow + ds*32 + lg*8);
    qfl[ds] = *(const f16x8*)(ql + qrow + ds*32 + lg*8);
  }

  f32x4 zero4 = {0.f,0.f,0.f,0.f};
  f32x4 accO[8];
  #pragma unroll
  for (int dc=0; dc<8; dc++) accO[dc] = zero4;
  float mrun[4], lrun[4];
  #pragma unroll
  for (int i=0;i<4;i++){ mrun[i] = -3.0e38f; lrun[i] = 0.0f; }

  const float SC_S = 0.08838834764831845f * (1.0f/(SC_QK*SC_QK));
  int nkt = 16 - bx;
  for (int kt=0; kt<nkt; kt++){
    #pragma unroll
    for (int pp=0; pp<2; pp++){
      int r = pp*32 + (tid>>4), c = (tid&15)*8;
      size_t go = (size_t)(b*S_N + kt*64 + r)*KD_N + kvh*D_N + c;
      *(f16x8*)&Ksh[r*136 + c] = *(const f16x8*)(kh + go);
      *(f16x8*)&Ksl[r*136 + c] = *(const f16x8*)(kl + go);
    }
    #pragma unroll
    for (int pp=0; pp<2; pp++){
      int r = pp*64 + (tid>>3), c = (tid&7)*8;
      size_t go = ((size_t)(b*HKV_N + kvh)*D_N + r)*S_N + kt*64 + c;
      *(f16x8*)&Vsh[r*72 + c] = *(const f16x8*)(vth + go);
      *(f16x8*)&Vsl[r*72 + c] = *(const f16x8*)(vtl + go);
    }
    __syncthreads();

    bool active = (kt <= qtile);
    if (active){
      f32x4 sacc[4];
      #pragma unroll
      for (int kc=0;kc<4;kc++){
        sacc[kc] = zero4;
        #pragma unroll
        for (int ds=0; ds<4; ds++){
          f16x8 kfh = *(const f16x8*)&Ksh[(kc*16 + l15)*136 + ds*32 + lg*8];
          f16x8 kfl = *(const f16x8*)&Ksl[(kc*16 + l15)*136 + ds*32 + lg*8];
          sacc[kc] = mfma16h(qfh[ds], kfh, sacc[kc]);
          sacc[kc] = mfma16h(qfh[ds], kfl, sacc[kc]);
          sacc[kc] = mfma16h(qfl[ds], kfh, sacc[kc]);
        }
      }

      float pv[4][4];
      bool maskT = (kt == qtile);
      #pragma unroll
      for (int kc=0;kc<4;kc++)
        #pragma unroll
        for (int i=0;i<4;i++){
          float sv = sacc[kc][i] * SC_S;
          if (maskT){
            int kg = kt*64 + kc*16 + l15;
            int qg = qrow0 + 4*lg + i;
            if (kg > qg) sv = -3.0e38f;
          }
          pv[kc][i] = sv;
        }

      #pragma unroll
      for (int i=0;i<4;i++){
        float mx = fmaxf(fmaxf(pv[0][i],pv[1][i]),fmaxf(pv[2][i],pv[3][i]));
        #pragma unroll
        for (int mm=1; mm<16; mm<<=1) mx = fmaxf(mx, __shfl_xor(mx, mm, 64));
        float mnew = fmaxf(mrun[i], mx);
        float corr = exp2f((mrun[i]-mnew)*1.44269504f);
        float ps = 0.f;
        #pragma unroll
        for (int kc=0;kc<4;kc++){
          float p = exp2f((pv[kc][i]-mnew)*1.44269504f);
          pv[kc][i] = p; ps += p;
        }
        #pragma unroll
        for (int mm=1; mm<16; mm<<=1) ps += __shfl_xor(ps, mm, 64);
        lrun[i] = lrun[i]*corr + ps;
        mrun[i] = mnew;
        #pragma unroll
        for (int dc=0;dc<8;dc++) accO[dc][i] *= corr;
      }

      #pragma unroll
      for (int kc=0;kc<4;kc++)
        #pragma unroll
        for (int i=0;i<4;i++){
          u16 hh, ll; split2h(pv[kc][i]*SC_P, hh, ll);
          Psh[wave][(4*lg+i)*72 + kc*16 + l15] = hh;
          Psl[wave][(4*lg+i)*72 + kc*16 + l15] = ll;
        }
      asm volatile("s_waitcnt lgkmcnt(0)" ::: "memory");
      __builtin_amdgcn_sched_barrier(0);

      #pragma unroll
      for (int ks=0; ks<2; ks++){
        f16x8 pfh = *(const f16x8*)&Psh[wave][l15*72 + ks*32 + lg*8];
        f16x8 pfl = *(const f16x8*)&Psl[wave][l15*72 + ks*32 + lg*8];
        #pragma unroll
        for (int dc=0; dc<8; dc++){
          f16x8 vfh = *(const f16x8*)&Vsh[(dc*16 + l15)*72 + ks*32 + lg*8];
          f16x8 vfl = *(const f16x8*)&Vsl[(dc*16 + l15)*72 + ks*32 + lg*8];
          accO[dc] = mfma16h(pfh, vfh, accO[dc]);
          accO[dc] = mfma16h(pfh, vfl, accO[dc]);
          accO[dc] = mfma16h(pfl, vfh, accO[dc]);
        }
      }
    }
    __syncthreads();
  }

  #pragma unroll
  for (int i=0;i<4;i++){
    float inv = 1.0f / (4096.0f * lrun[i]);
    size_t orow = (size_t)(b*S_N + qrow0 + 4*lg + i)*QD_N + h*D_N;
    #pragma unroll
    for (int dc=0; dc<8; dc++){
      u16 hh, ll; split2h(accO[dc][i]*inv, hh, ll);
      aoh[orow + dc*16 + l15] = hh;
      aol[orow + dc*16 + l15] = ll;
    }
  }
}

// ---------------- router
__global__ __launch_bounds__(256) void router_kernel(
    const float* __restrict__ resid2, const float* __restrict__ ln2w,
    const float* __restrict__ gwT, const float* __restrict__ ebias,
    int* __restrict__ tkIdx, float* __restrict__ tkW, int* __restrict__ counts)
{
  int t = blockIdx.x, tid = threadIdx.x;
  __shared__ float xs[H_N];
  __shared__ float red[4];
  __shared__ float sc[E_N];
  const float4* x4 = (const float4*)(resid2 + (size_t)t*H_N);
  float4 a = x4[2*tid], b = x4[2*tid+1];
  float ss = a.x*a.x+a.y*a.y+a.z*a.z+a.w*a.w + b.x*b.x+b.y*b.y+b.z*b.z+b.w*b.w;
  #pragma unroll
  for (int m=32;m>=1;m>>=1) ss += __shfl_xor(ss,m,64);
  if ((tid&63)==0) red[tid>>6]=ss;
  __syncthreads();
  float scale = rsqrtf((red[0]+red[1]+red[2]+red[3])*(1.0f/H_N) + 1e-6f);
  const float4* w4 = (const float4*)ln2w;
  float4 wa = w4[2*tid], wb = w4[2*tid+1];
  xs[tid*8+0]=a.x*scale*wa.x; xs[tid*8+1]=a.y*scale*wa.y;
  xs[tid*8+2]=a.z*scale*wa.z; xs[tid*8+3]=a.w*scale*wa.w;
  xs[tid*8+4]=b.x*scale*wb.x; xs[tid*8+5]=b.y*scale*wb.y;
  xs[tid*8+6]=b.z*scale*wb.z; xs[tid*8+7]=b.w*scale*wb.w;
  __syncthreads();
  int wave = tid>>6, lane = tid&63;
  const float4* xv4 = (const float4*)xs;
  #pragma unroll
  for (int ei=0; ei<8; ei++){
    int e = wave*8 + ei;
    const float4* g4 = (const float4*)(gwT + (size_t)e*H_N);
    float acc = 0.f;
    #pragma unroll
    for (int it=0; it<8; it++){
      int idx = it*64 + lane;
      float4 g = g4[idx], xv = xv4[idx];
      acc += g.x*xv.x + g.y*xv.y + g.z*xv.z + g.w*xv.w;
    }
    #pragma unroll
    for (int m=32;m>=1;m>>=1) acc += __shfl_xor(acc,m,64);
    if (lane==0) sc[e] = 1.0f/(1.0f+__expf(-acc));
  }
  __syncthreads();
  if (tid==0){
    float sb[E_N];
    #pragma unroll
    for (int e2=0;e2<E_N;e2++) sb[e2] = sc[e2]+ebias[e2];
    int ch[4]; float wv[4]; float wsum=0.f;
    for (int j=0;j<4;j++){
      int best=0; float bv=-3.0e38f;
      for (int e2=0;e2<E_N;e2++) if (sb[e2] > bv){ bv=sb[e2]; best=e2; }
      ch[j]=best; wv[j]=sc[best]; wsum+=sc[best]; sb[best]=-3.0e38f;
    }
    float invs = 1.0f/wsum;
    for (int j=0;j<4;j++){
      tkIdx[t*4+j]=ch[j]; tkW[t*4+j]=wv[j]*invs;
      atomicAdd(&counts[ch[j]], 1);
    }
  }
}

// ---------------- deterministic capacity ranking
__global__ void moe_count_kernel(const int* __restrict__ tki, int* __restrict__ G){
  __shared__ int cnt[E_N];
  int g = blockIdx.x, t = threadIdx.x;
  if (t < E_N) cnt[t] = 0;
  __syncthreads();
  atomicAdd(&cnt[tki[g*RGRP + t]], 1);
  __syncthreads();
  if (t < E_N) G[g*E_N + t] = cnt[t];
}

__global__ void moe_scan_kernel(const int* __restrict__ G, int* __restrict__ base,
                                int* __restrict__ starts){
  __shared__ int tot[E_N];
  int e = threadIdx.x;
  if (e < E_N){
    int run = 0;
    for (int g=0; g<NGRP; g++){ base[g*E_N+e] = run; run += G[g*E_N+e]; }
    tot[e] = run < CAP_N ? run : CAP_N;
  }
  __syncthreads();
  if (e==0){
    int run=0;
    for (int x=0; x<E_N; x++){ starts[x]=run; run+=tot[x]; }
  }
}

__global__ void moe_assign_kernel(const int* __restrict__ tki,
                                  const int* __restrict__ base, const int* __restrict__ starts,
                                  int* __restrict__ ptok, int* __restrict__ tok2slot){
  __shared__ int eL[RGRP];
  int g = blockIdx.x, t = threadIdx.x;
  int f = g*RGRP + t;
  int e = tki[f];
  eL[t] = e;
  __syncthreads();
  int r = 0;
  for (int j=0; j<RGRP; j++) r += ((j < t) && (eL[j]==e)) ? 1 : 0;
  int pos = base[g*E_N + e] + r;
  if (pos < CAP_N){
    int slot = starts[e] + pos;
    ptok[slot] = f >> 2;
    tok2slot[f] = slot;
  } else {
    tok2slot[f] = -1;
  }
}

// ---------------- combine
__global__ __launch_bounds__(256) void moe_combine(const int* __restrict__ tok2slot,
                                                   const float* __restrict__ tkw,
                                                   const bf16u* __restrict__ obuf,
                                                   float* __restrict__ outp){
  int t = blockIdx.x;
  int c0 = threadIdx.x*8;
  float acc[8];
  float4* o4 = (float4*)(outp + (size_t)t*H_N + c0);
  float4 v0 = o4[0], v1 = o4[1];
  acc[0]=v0.x; acc[1]=v0.y; acc[2]=v0.z; acc[3]=v0.w;
  acc[4]=v1.x; acc[5]=v1.y; acc[6]=v1.z; acc[7]=v1.w;
  #pragma unroll
  for (int j=0;j<4;j++){
    int slot = tok2slot[t*4+j];
    if (slot >= 0){
      float w = tkw[t*4+j];
      bf16x8 ob = *(const bf16x8*)(obuf + (size_t)slot*H_N + c0);
      #pragma unroll
      for (int q=0;q<8;q++) acc[q] += w * bf2f((bf16u)ob[q]);
    }
  }
  v0.x=acc[0]; v0.y=acc[1]; v0.z=acc[2]; v0.w=acc[3];
  v1.x=acc[4]; v1.y=acc[5]; v1.z=acc[6]; v1.w=acc[7];
  o4[0]=v0; o4[1]=v1;
}

extern "C" void kernel_launch(void* const* d_in, const int* in_sizes, int n_in,
                              void* d_out, int out_size, void* d_ws, size_t ws_size,
                              hipStream_t stream) {
  (void)in_sizes; (void)n_in; (void)out_size; (void)ws_size;
  const float* hidden    = (const float*)d_in[0];
  const int*   positions = (const int*)d_in[1];
  const float* ln1w = (const float*)d_in[2];
  const float* ln2w = (const float*)d_in[3];
  const float* wq   = (const float*)d_in[4];
  const float* wk   = (const float*)d_in[5];
  const float* wv   = (const float*)d_in[6];
  const float* wo   = (const float*)d_in[7];
  const float* qnw  = (const float*)d_in[8];
  const float* knw  = (const float*)d_in[9];
  const float* gatew= (const float*)d_in[10];
  const float* ebias= (const float*)d_in[11];
  const float* wge  = (const float*)d_in[12];
  const float* wue  = (const float*)d_in[13];
  const float* wde  = (const float*)d_in[14];
  const float* wsg  = (const float*)d_in[15];
  const float* wsu  = (const float*)d_in[16];
  const float* wsd  = (const float*)d_in[17];
  float* outp = (float*)d_out;

  char* wsb = (char*)d_ws;
  size_t off = 0;
  auto take = [&](size_t bytes)->char*{
    char* p = wsb + off; off += (bytes + 255) & ~(size_t)255; return p;
  };
  u16* qkvTh = (u16*)take(3072ull*2048*2);
  u16* qkvTl = (u16*)take(3072ull*2048*2);
  u16* woTh = (u16*)take(2048ull*2048*2);
  u16* woTl = (u16*)take(2048ull*2048*2);
  u16* wsgT = (u16*)take(1024ull*2048*2);
  u16* wsuT = (u16*)take(1024ull*2048*2);
  u16* wsdT = (u16*)take(2048ull*1024*2);
  u16* wgeT = (u16*)take(32ull*512*2048*2);
  u16* wueT = (u16*)take(32ull*512*2048*2);
  u16* wdeT = (u16*)take(32ull*2048*512*2);
  float* gwT = (float*)take(32ull*2048*4);
  u16* h1h  = (u16*)take((size_t)T_N*H_N*2);
  u16* h1l  = (u16*)take((size_t)T_N*H_N*2);
  float* qkv32 = (float*)take((size_t)T_N*QKV_N*4);
  u16* qHh  = (u16*)take((size_t)T_N*QD_N*2);
  u16* qHl  = (u16*)take((size_t)T_N*QD_N*2);
  u16* kHh  = (u16*)take((size_t)T_N*KD_N*2);
  u16* kHl  = (u16*)take((size_t)T_N*KD_N*2);
  u16* vtHh = (u16*)take((size_t)T_N*KD_N*2);
  u16* vtHl = (u16*)take((size_t)T_N*KD_N*2);
  u16* aoh  = (u16*)take((size_t)T_N*QD_N*2);
  u16* aol  = (u16*)take((size_t)T_N*QD_N*2);
  float* resid2=(float*)take((size_t)T_N*H_N*4);
  u16* h2   = (u16*)take((size_t)T_N*H_N*2);
  u16* interS=(u16*)take((size_t)T_N*SIM_N*2);
  u16* minter=(u16*)take((size_t)NFLAT*IM_N*2);
  bf16u* obuf = (bf16u*)take((size_t)NFLAT*H_N*2);
  int*   tki  = (int*)take((size_t)NFLAT*4);
  float* tkw  = (float*)take((size_t)NFLAT*4);
  int*   counts=(int*)take(E_N*4);
  int*   Gcnt = (int*)take((size_t)NGRP*E_N*4);
  int*   Gbase= (int*)take((size_t)NGRP*E_N*4);
  int*   starts=(int*)take(E_N*4);
  int*   ptok = (int*)take((size_t)NFLAT*4);
  int*   tok2slot = (int*)take((size_t)NFLAT*4);

  hipMemsetAsync(counts, 0, 256, stream);

  dim3 tb(32,8);
  transpose_split16_g<<<dim3(32,32), 256, 0, stream>>>(wq, qkvTh, qkvTl, 2048, 2048, SC_W);
  transpose_split16_g<<<dim3(32,8),  256, 0, stream>>>(wk, qkvTh + 2048ull*2048, qkvTl + 2048ull*2048, 2048, 512, SC_W);
  transpose_split16_g<<<dim3(32,8),  256, 0, stream>>>(wv, qkvTh + 2560ull*2048, qkvTl + 2560ull*2048, 2048, 512, SC_W);
  transpose_split16_g<<<dim3(32,32), 256, 0, stream>>>(wo, woTh, woTl, 2048, 2048, SC_W);
  transpose_cvt_g<<<dim3(32,16,1), 256, 0, stream>>>(wsg, wsgT, 2048, 1024);
  transpose_cvt_g<<<dim3(32,16,1), 256, 0, stream>>>(wsu, wsuT, 2048, 1024);
  transpose_cvt_g<<<dim3(16,32,1), 256, 0, stream>>>(wsd, wsdT, 1024, 2048);
  transpose_cvt_g<<<dim3(32,8,32), 256, 0, stream>>>(wge, wgeT, 2048, 512);
  transpose_cvt_g<<<dim3(32,8,32), 256, 0, stream>>>(wue, wueT, 2048, 512);
  transpose_cvt_g<<<dim3(8,32,32), 256, 0, stream>>>(wde, wdeT, 512, 2048);
  transpose_f32<<<dim3(64,1,1), tb, 0, stream>>>(gatew, gwT, 2048, 32);

  rmsnorm_f16split<<<T_N, 256, 0, stream>>>(hidden, ln1w, h1h, h1l);
  gemm_bt8<1,true><<<dim3(16,24), 512, 0, stream>>>(h1h, h1l, qkvTh, qkvTl, nullptr, qkv32, nullptr, OSC_QKV, QKV_N, H_N);
  qknorm_rope_split<<<dim3(T_N,20), 64, 0, stream>>>(qkv32, qnw, knw, positions, qHh, qHl, kHh, kHl);
  transpose_v_split<<<dim3(32,4,8), tb, 0, stream>>>(qkv32, vtHh, vtHl);
  attn_kernel<<<dim3(8,32), 512, 0, stream>>>(qHh, qHl, kHh, kHl, vtHh, vtHl, aoh, aol);
  gemm_bt8<1,true><<<dim3(16,16), 512, 0, stream>>>(aoh, aol, woTh, woTl, nullptr, resid2, hidden, OSC_OPJ, H_N, QD_N);
  rmsnorm_bf16<<<T_N, 256, 0, stream>>>(resid2, ln2w, (bf16u*)h2);
  gemm_bt8<2,false><<<dim3(16,8), 512, 0, stream>>>(h2, nullptr, wsgT, nullptr, wsuT, interS, nullptr, 1.0f, SIM_N, H_N);
  gemm_bt8<1,false><<<dim3(16,16), 512, 0, stream>>>(interS, nullptr, wsdT, nullptr, nullptr, outp, resid2, 1.0f, H_N, SIM_N);
  router_kernel<<<T_N, 256, 0, stream>>>(resid2, ln2w, gwT, ebias, tki, tkw, counts);
  moe_count_kernel<<<NGRP, RGRP, 0, stream>>>(tki, Gcnt);
  moe_scan_kernel<<<1, 64, 0, stream>>>(Gcnt, Gbase, starts);
  moe_assign_kernel<<<NGRP, RGRP, 0, stream>>>(tki, Gbase, starts, ptok, tok2slot);
  moe_gu8w<<<dim3(4,4,32), 512, 0, stream>>>(h2, wgeT, wueT, minter, starts, counts, ptok);
  moe_down8w<<<dim3(4,16,32), 512, 0, stream>>>(minter, wdeT, obuf, starts, counts);
  moe_combine<<<T_N, 256, 0, stream>>>(tok2slot, tkw, obuf, outp);
}